// Round 2
// baseline (245.509 us; speedup 1.0000x reference)
//
#include <hip/hip_runtime.h>
#include <hip/hip_bf16.h>

typedef __bf16 bf16;
typedef __bf16 bf16x8 __attribute__((ext_vector_type(8)));
typedef __bf16 bf16x4 __attribute__((ext_vector_type(4)));
typedef float  f32x4  __attribute__((ext_vector_type(4)));

#define MFMA16(a,b,c) __builtin_amdgcn_mfma_f32_16x16x32_bf16(a, b, c, 0, 0, 0)

// async global->LDS, 16B per lane; lds dst is wave-uniform base + lane*16
__device__ __forceinline__ void gl2lds16(const bf16* g, bf16* l) {
    __builtin_amdgcn_global_load_lds(
        (__attribute__((address_space(1))) void*)g,
        (__attribute__((address_space(3))) void*)l, 16, 0, 0);
}

// ---------------------------------------------------------------------------
// Fused prep: blocks [0,6144) fp32->bf16 cvt of q|k|v; [6144,6912) Wq/Wk/Wv
// transpose; [6912,7168) Wo transpose.
// ---------------------------------------------------------------------------
__global__ __launch_bounds__(256)
void prep_kernel(const float* __restrict__ q, const float* __restrict__ k,
                 const float* __restrict__ v, const float* __restrict__ Wq,
                 const float* __restrict__ Wk, const float* __restrict__ Wv,
                 const float* __restrict__ Wo, bf16* __restrict__ Xcat,
                 bf16* __restrict__ Wqkv, bf16* __restrict__ Wot)
{
    __shared__ bf16 Tl[64][72];
    const int bid = blockIdx.x;
    const int tid = threadIdx.x;

    if (bid < 6144) {
        int gidx = bid * 256 + tid;                   // vec8 group
        int t    = gidx >> 19;
        int off  = (gidx & 0x7FFFF) * 8;
        const float* src = (t == 0) ? q : (t == 1) ? k : v;
        const float4 f0 = *(const float4*)&src[off];
        const float4 f1 = *(const float4*)&src[off + 4];
        bf16x8 p = { (bf16)f0.x, (bf16)f0.y, (bf16)f0.z, (bf16)f0.w,
                     (bf16)f1.x, (bf16)f1.y, (bf16)f1.z, (bf16)f1.w };
        *(bf16x8*)&Xcat[(size_t)gidx * 8] = p;
        return;
    }
    if (bid < 6912) {
        // W[h][k][e] fp32 -> Wqkv[t*1Mi + (h*64+e)*1024 + k]
        int idx = bid - 6144;                         // 768
        int x = idx & 15, z = idx >> 4;               // x: k-tile, z = t*16+h
        int t = z >> 4, h = z & 15;
        const float* inp = ((t == 0) ? Wq : (t == 1) ? Wk : Wv) + (size_t)h * 65536;
        bf16* outp = Wqkv + (size_t)t * 1024 * 1024 + (size_t)h * 65536;
        int r0 = x * 64;
        #pragma unroll
        for (int i = 0; i < 2; i++) {
            int s = tid + i * 256;
            int r = s >> 3, c8 = (s & 7) * 8;
            const float* ap = &inp[(size_t)(r0 + r) * 64 + c8];
            float4 f0 = *(const float4*)ap;
            float4 f1 = *(const float4*)(ap + 4);
            bf16x8 p = { (bf16)f0.x, (bf16)f0.y, (bf16)f0.z, (bf16)f0.w,
                         (bf16)f1.x, (bf16)f1.y, (bf16)f1.z, (bf16)f1.w };
            *(bf16x8*)&Tl[r][c8] = p;
        }
        __syncthreads();
        #pragma unroll
        for (int i = 0; i < 2; i++) {
            int s = tid + i * 256;
            int c = s >> 3, r8 = (s & 7) * 8;
            bf16x8 p;
            #pragma unroll
            for (int j = 0; j < 8; j++) p[j] = Tl[r8 + j][c];
            *(bf16x8*)&outp[(size_t)c * 1024 + r0 + r8] = p;
        }
        return;
    }
    // Wo[h][e][o] fp32 -> Wot[o][h*64+e]
    {
        int idx = bid - 6912;                         // 256
        int y = idx & 15, h = idx >> 4;
        int c0 = y * 64;
        const float* inp = Wo + (size_t)h * 65536;
        bf16* outp = Wot + (size_t)h * 64;
        #pragma unroll
        for (int i = 0; i < 2; i++) {
            int s = tid + i * 256;
            int r = s >> 3, c8 = (s & 7) * 8;
            const float* ap = &inp[(size_t)r * 1024 + c0 + c8];
            float4 f0 = *(const float4*)ap;
            float4 f1 = *(const float4*)(ap + 4);
            bf16x8 p = { (bf16)f0.x, (bf16)f0.y, (bf16)f0.z, (bf16)f0.w,
                         (bf16)f1.x, (bf16)f1.y, (bf16)f1.z, (bf16)f1.w };
            *(bf16x8*)&Tl[r][c8] = p;
        }
        __syncthreads();
        #pragma unroll
        for (int i = 0; i < 2; i++) {
            int s = tid + i * 256;
            int c = s >> 3, r8 = (s & 7) * 8;
            bf16x8 p;
            #pragma unroll
            for (int j = 0; j < 8; j++) p[j] = Tl[r8 + j][c];
            *(bf16x8*)&outp[(size_t)(c0 + c) * 1024 + r8] = p;
        }
    }
}

// ---------------------------------------------------------------------------
// Fused QKV projection GEMM: grid (96, 8); slab = blockIdx.x>>5 in {0,1,2}.
// slab 0 -> Qproj (scaled), slab 1 -> Kproj, slab 2 -> Vt transposed epilogue
// with the 32-block kv PERMUTATION: pos(s) = (s&~31) | ((s>>2)&3)*8 |
// ((s>>4)&1)*4 | (s&3), so attn V-fragments are contiguous b128 reads.
// ---------------------------------------------------------------------------
__global__ __launch_bounds__(256)
void qkv_gemm(const bf16* __restrict__ Xcat, const bf16* __restrict__ Wqkv,
              bf16* __restrict__ Cq, bf16* __restrict__ Ck, bf16* __restrict__ Vt,
              float qscale)
{
    __shared__ bf16 Al[128 * 64];
    __shared__ bf16 Bl[128 * 64];
    const int slab  = blockIdx.x >> 5;
    const int mbase = (blockIdx.x & 31) * 128;
    const int nbase = blockIdx.y * 128;
    const int tid = threadIdx.x;
    const int w = tid >> 6, lane = tid & 63;
    const int lm = lane & 15, q4 = lane >> 4;
    const int wr = (w >> 1) * 64, wc = (w & 1) * 64;
    const int lrow = lane >> 3, lsw = ((lane & 7) ^ lrow) * 8;

    const bf16* A  = Xcat + (size_t)slab * 4096 * 1024;
    const bf16* Bt = Wqkv + (size_t)slab * 1024 * 1024;

    f32x4 acc[4][4] = {};

    for (int k0 = 0; k0 < 1024; k0 += 64) {
        __syncthreads();
        #pragma unroll
        for (int i = 0; i < 4; i++) {
            int c = w * 4 + i;
            gl2lds16(&A [(size_t)(mbase + c * 8 + lrow) * 1024 + k0 + lsw], &Al[c * 512]);
            gl2lds16(&Bt[(size_t)(nbase + c * 8 + lrow) * 1024 + k0 + lsw], &Bl[c * 512]);
        }
        __syncthreads();
        #pragma unroll
        for (int kk2 = 0; kk2 < 2; kk2++) {
            bf16x8 a[4], bfr[4];
            const int g = ((kk2 * 4 + q4) ^ (lm & 7)) * 8;
            #pragma unroll
            for (int i = 0; i < 4; i++) a[i]   = *(const bf16x8*)&Al[(wr + i * 16 + lm) * 64 + g];
            #pragma unroll
            for (int j = 0; j < 4; j++) bfr[j] = *(const bf16x8*)&Bl[(wc + j * 16 + lm) * 64 + g];
            #pragma unroll
            for (int i = 0; i < 4; i++)
                #pragma unroll
                for (int j = 0; j < 4; j++)
                    acc[i][j] = MFMA16(a[i], bfr[j], acc[i][j]);
        }
    }

    if (slab == 2) {
        #pragma unroll
        for (int i = 0; i < 4; i++)
            #pragma unroll
            for (int j = 0; j < 4; j++) {
                int s0  = mbase + wr + i * 16 + q4 * 4;      // kv, multiple of 4
                int col = nbase + wc + j * 16 + lm;          // e
                int sp  = (s0 & ~31) | (((s0 >> 2) & 3) * 8) | (((s0 >> 4) & 1) * 4);
                bf16x4 p = { (bf16)acc[i][j][0], (bf16)acc[i][j][1],
                             (bf16)acc[i][j][2], (bf16)acc[i][j][3] };
                *(bf16x4*)&Vt[(size_t)col * 4096 + sp] = p;
            }
    } else {
        bf16* C = (slab == 0) ? Cq : Ck;
        const float scale = (slab == 0) ? qscale : 1.0f;
        #pragma unroll
        for (int i = 0; i < 4; i++)
            #pragma unroll
            for (int j = 0; j < 4; j++)
                #pragma unroll
                for (int r = 0; r < 4; r++) {
                    int row = mbase + wr + i * 16 + q4 * 4 + r;
                    int col = nbase + wc + j * 16 + lm;
                    C[(size_t)row * 1024 + col] = (bf16)(acc[i][j][r] * scale);
                }
    }
}

// ---------------------------------------------------------------------------
// Output projection, 64x128 (MxN) tiles, grid (64, 8) = 2 blocks/CU.
// out[4096,1024] fp32 = Hd bf16 @ Wot^T
// ---------------------------------------------------------------------------
__global__ __launch_bounds__(256)
void outproj_gemm(const bf16* __restrict__ A, const bf16* __restrict__ Bt,
                  float* __restrict__ C)
{
    __shared__ bf16 Al[64 * 64];
    __shared__ bf16 Bl[128 * 64];
    const int mbase = blockIdx.x * 64;
    const int nbase = blockIdx.y * 128;
    const int tid = threadIdx.x;
    const int w = tid >> 6, lane = tid & 63;
    const int lm = lane & 15, q4 = lane >> 4;
    const int wm = (w >> 1) * 32, wn = (w & 1) * 64;   // 32x64 per wave
    const int lrow = lane >> 3, lsw = ((lane & 7) ^ lrow) * 8;

    f32x4 acc[2][4] = {};

    for (int k0 = 0; k0 < 1024; k0 += 64) {
        __syncthreads();
        #pragma unroll
        for (int i = 0; i < 2; i++) {
            int c = w * 2 + i;                          // 8 chunks of 8 rows
            gl2lds16(&A[(size_t)(mbase + c * 8 + lrow) * 1024 + k0 + lsw], &Al[c * 512]);
        }
        #pragma unroll
        for (int i = 0; i < 4; i++) {
            int c = w * 4 + i;                          // 16 chunks of 8 rows
            gl2lds16(&Bt[(size_t)(nbase + c * 8 + lrow) * 1024 + k0 + lsw], &Bl[c * 512]);
        }
        __syncthreads();
        #pragma unroll
        for (int kk2 = 0; kk2 < 2; kk2++) {
            bf16x8 a[2], bfr[4];
            const int g = ((kk2 * 4 + q4) ^ (lm & 7)) * 8;
            #pragma unroll
            for (int i = 0; i < 2; i++) a[i]   = *(const bf16x8*)&Al[(wm + i * 16 + lm) * 64 + g];
            #pragma unroll
            for (int j = 0; j < 4; j++) bfr[j] = *(const bf16x8*)&Bl[(wn + j * 16 + lm) * 64 + g];
            #pragma unroll
            for (int i = 0; i < 2; i++)
                #pragma unroll
                for (int j = 0; j < 4; j++)
                    acc[i][j] = MFMA16(a[i], bfr[j], acc[i][j]);
        }
    }

    #pragma unroll
    for (int i = 0; i < 2; i++)
        #pragma unroll
        for (int j = 0; j < 4; j++)
            #pragma unroll
            for (int r = 0; r < 4; r++) {
                int row = mbase + wm + i * 16 + q4 * 4 + r;
                int col = nbase + wn + j * 16 + lm;
                C[(size_t)row * 1024 + col] = acc[i][j][r];
            }
}

// ---------------------------------------------------------------------------
// Flash attention, register-P + staged K + permuted V + double buffer.
//   S^T = MFMA(A=K_lds, B=Q_regs)   -> lane holds P for q = lane&15
//   P packed in regs as the PV A-operand (permuted k-order);
//   V pre-permuted in global so V-frags are contiguous b128 LDS reads.
// Round-2 changes (round-1 showed the per-CU LDS read pipe at ~71% while
// occupancy doubling was a no-op -> LDS-read-throughput bound):
//   * 4 waves/block = 2 q-pairs x 2 kv-halves: each wave does 32 q-rows x
//     32 kv of each tile -> 8 ds_read_b128 per 18 MFMA (was 16/18). Halves
//     per-CU LDS read traffic at unchanged 16 waves/CU occupancy.
//     kv-halves merged once post-loop via LDS (reusing K/V buffers).
//   * per-block kv start-offset STAGGER: blocks on a CU were phase-locked
//     (S/exp/PV phases collide on the same pipe); softmax sum is
//     order-invariant so each block starts its kv sweep at a different tile.
//   * keep: Lacc denom-via-MFMA, s_setprio around MFMA clusters.
// ---------------------------------------------------------------------------
__global__ __launch_bounds__(256, 4)
void attn_kernel(const bf16* __restrict__ Qp, const bf16* __restrict__ Kp,
                 const bf16* __restrict__ Vt, bf16* __restrict__ Hd)
{
    __shared__ bf16 Kl[2][64 * 64];
    __shared__ bf16 Vl[2][64 * 64];

    const int qt = blockIdx.x, b = blockIdx.y, h = blockIdx.z;
    const int qbase = qt * 64;
    const int tid  = threadIdx.x;
    const int w    = tid >> 6, lane = tid & 63;
    const int p    = w & 1;          // q-pair: rows [p*32, p*32+32)
    const int kvh  = w >> 1;         // kv half of each 64-wide tile
    const int lm   = lane & 15, q4 = lane >> 4;
    const int lrow = lane >> 3, lsw = ((lane & 7) ^ lrow) * 8;

    const bf16* Qh = Qp + (size_t)(b * 2048 + qbase + p * 32) * 1024 + h * 64;
    const bf16* Kh = Kp + (size_t)(b * 2048) * 1024 + h * 64;
    const bf16* Vh = Vt + (size_t)(h * 64) * 4096 + b * 2048;

    // Q fragments (loop-invariant), B-operand layout: n=lm, k=q4*8+j
    bf16x8 Qf[2][2];
    #pragma unroll
    for (int i = 0; i < 2; i++)
        #pragma unroll
        for (int kk2 = 0; kk2 < 2; kk2++)
            Qf[i][kk2] = *(const bf16x8*)&Qh[(size_t)(i * 16 + lm) * 1024 + kk2 * 32 + q4 * 8];

    const bf16 one = (bf16)1.0f;
    const bf16x8 ones = { one, one, one, one, one, one, one, one };

    f32x4 O[2][4] = {};
    f32x4 Lacc[2] = {};   // row-sums of P (softmax denom), same row layout as O

    // stage kv-tile kt into buffer d (K rows=kv, V rows=e; identical pattern)
    auto stage = [&](int kt, int d) {
        #pragma unroll
        for (int i = 0; i < 2; i++) {
            int c = w * 2 + i;                           // 8 chunks of 8 rows
            gl2lds16(&Kh[(size_t)(kt * 64 + c * 8 + lrow) * 1024 + lsw], &Kl[d][c * 512]);
            gl2lds16(&Vh[(size_t)(c * 8 + lrow) * 4096 + kt * 64 + lsw], &Vl[d][c * 512]);
        }
    };

    // kv iteration origin stagger (order-invariant sum; decorrelates the
    // per-tile phases of co-resident blocks so pipes overlap across waves)
    const int phase = (qt * 3 + h * 5 + b * 16) & 31;

    stage(phase, 0);

    for (int it = 0; it < 32; it++) {
        __syncthreads();                                 // buf[it&1] ready
        if (it < 31) stage((it + 1 + phase) & 31, (it + 1) & 1);
        const bf16* Kd = &Kl[it & 1][0];
        const bf16* Vd = &Vl[it & 1][0];

        // S^T for this wave's kv-half: ctp in {kvh*2, kvh*2+1}
        f32x4 St[2][2] = {};
        __builtin_amdgcn_s_setprio(1);
        #pragma unroll
        for (int c2 = 0; c2 < 2; c2++) {
            const int ctp = kvh * 2 + c2;
            #pragma unroll
            for (int kk2 = 0; kk2 < 2; kk2++) {
                const int g = ((kk2 * 4 + q4) ^ (lm & 7)) * 8;
                bf16x8 kf = *(const bf16x8*)&Kd[(ctp * 16 + lm) * 64 + g];
                #pragma unroll
                for (int i = 0; i < 2; i++)
                    St[i][c2] = MFMA16(kf, Qf[i][kk2], St[i][c2]);
            }
        }
        __builtin_amdgcn_s_setprio(0);

        // P = exp2(S^T) packed into A-slots for this kv-32 chunk (kk4 = kvh)
        bf16x8 Pf[2];
        #pragma unroll
        for (int i = 0; i < 2; i++)
            #pragma unroll
            for (int j = 0; j < 8; j++)
                Pf[i][j] = (bf16)__builtin_amdgcn_exp2f(St[i][j >> 2][j & 3]);

        __builtin_amdgcn_s_setprio(1);
        #pragma unroll
        for (int i = 0; i < 2; i++) Lacc[i] = MFMA16(Pf[i], ones, Lacc[i]);
        const int gv = ((kvh * 4 + q4) ^ (lm & 7)) * 8;
        #pragma unroll
        for (int et = 0; et < 4; et++) {
            bf16x8 vf = *(const bf16x8*)&Vd[(et * 16 + lm) * 64 + gv];
            #pragma unroll
            for (int i = 0; i < 2; i++)
                O[i][et] = MFMA16(Pf[i], vf, O[i][et]);
        }
        __builtin_amdgcn_s_setprio(0);
    }

    // ---- merge the two kv-halves via LDS (reuse Kl/Vl; 16 KB + 256 B) ----
    __syncthreads();                       // last tile's reads done
    float* Ol = (float*)&Kl[0][0];         // [p][32 rows][64 cols] f32
    float* Ll = (float*)&Vl[0][0];         // [p][32 rows] f32
    if (kvh == 1) {
        #pragma unroll
        for (int i = 0; i < 2; i++)
            #pragma unroll
            for (int et = 0; et < 4; et++)
                #pragma unroll
                for (int r = 0; r < 4; r++)
                    Ol[p * 2048 + (i * 16 + q4 * 4 + r) * 64 + et * 16 + lm] = O[i][et][r];
        if (lm == 0) {
            #pragma unroll
            for (int i = 0; i < 2; i++)
                #pragma unroll
                for (int r = 0; r < 4; r++)
                    Ll[p * 32 + i * 16 + q4 * 4 + r] = Lacc[i][r];
        }
    }
    __syncthreads();
    if (kvh == 0) {
        #pragma unroll
        for (int i = 0; i < 2; i++) {
            float rl[4];
            #pragma unroll
            for (int r = 0; r < 4; r++)
                rl[r] = 1.0f / (Lacc[i][r] + Ll[p * 32 + i * 16 + q4 * 4 + r]);
            #pragma unroll
            for (int et = 0; et < 4; et++)
                #pragma unroll
                for (int r = 0; r < 4; r++) {
                    float o = O[i][et][r] +
                              Ol[p * 2048 + (i * 16 + q4 * 4 + r) * 64 + et * 16 + lm];
                    int row = b * 2048 + qbase + p * 32 + i * 16 + q4 * 4 + r;
                    Hd[(size_t)row * 1024 + h * 64 + et * 16 + lm] = (bf16)(o * rl[r]);
                }
        }
    }
}

extern "C" void kernel_launch(void* const* d_in, const int* in_sizes, int n_in,
                              void* d_out, int out_size, void* d_ws, size_t ws_size,
                              hipStream_t stream)
{
    const float* q  = (const float*)d_in[0];
    const float* k  = (const float*)d_in[1];
    const float* v  = (const float*)d_in[2];
    const float* Wq = (const float*)d_in[3];
    const float* Wk = (const float*)d_in[4];
    const float* Wv = (const float*)d_in[5];
    const float* Wo = (const float*)d_in[6];
    float* out = (float*)d_out;

    // ws (bf16 elems, Mi = 1024*1024; 24Mi = 48 MB):
    //  [ 0, 4) qb -> Hd (attn out; qb dead after qkv_gemm)   [ 4, 8) kb
    //  [ 8,12) vb    [12,15) Wqkv   [15,16) Wot   [16,20) Qproj   [20,24) Kproj
    // Vt (bf16, 8 MB, kv-permuted) lives in d_out (16 MB fp32), overwritten
    // by outproj at the very end.
    const size_t Mi = 1024 * 1024;
    bf16* Xcat  = (bf16*)d_ws;
    bf16* Hd    = Xcat;                   // alias qb
    bf16* Wqkv  = Xcat + 12 * Mi;
    bf16* Wot   = Xcat + 15 * Mi;
    bf16* Qproj = Xcat + 16 * Mi;
    bf16* Kproj = Xcat + 20 * Mi;
    bf16* Vtb   = (bf16*)d_out;

    const float qscale = 0.125f * 1.4426950408889634f;  // 1/sqrt(64) * log2(e)

    prep_kernel<<<7168, 256, 0, stream>>>(q, k, v, Wq, Wk, Wv, Wo, Xcat, Wqkv, Wot);
    qkv_gemm<<<dim3(96, 8), 256, 0, stream>>>(Xcat, Wqkv, Qproj, Kproj, Vtb, qscale);
    attn_kernel<<<dim3(32, 2, 16), 256, 0, stream>>>(Qproj, Kproj, Vtb, Hd);
    outproj_gemm<<<dim3(64, 8), 256, 0, stream>>>(Hd, Wot, out);
}

// Round 3
// 211.004 us; speedup vs baseline: 1.1635x; 1.1635x over previous
//
#include <hip/hip_runtime.h>
#include <hip/hip_bf16.h>

typedef __bf16 bf16;
typedef __bf16 bf16x8 __attribute__((ext_vector_type(8)));
typedef __bf16 bf16x4 __attribute__((ext_vector_type(4)));
typedef float  f32x4  __attribute__((ext_vector_type(4)));

#define MFMA16(a,b,c) __builtin_amdgcn_mfma_f32_16x16x32_bf16(a, b, c, 0, 0, 0)

// async global->LDS, 16B per lane; lds dst is wave-uniform base + lane*16
__device__ __forceinline__ void gl2lds16(const bf16* g, bf16* l) {
    __builtin_amdgcn_global_load_lds(
        (__attribute__((address_space(1))) void*)g,
        (__attribute__((address_space(3))) void*)l, 16, 0, 0);
}

// ---------------------------------------------------------------------------
// Fused prep: blocks [0,6144) fp32->bf16 cvt of q|k|v; [6144,6912) Wq/Wk/Wv
// transpose; [6912,7168) Wo transpose.
// ---------------------------------------------------------------------------
__global__ __launch_bounds__(256)
void prep_kernel(const float* __restrict__ q, const float* __restrict__ k,
                 const float* __restrict__ v, const float* __restrict__ Wq,
                 const float* __restrict__ Wk, const float* __restrict__ Wv,
                 const float* __restrict__ Wo, bf16* __restrict__ Xcat,
                 bf16* __restrict__ Wqkv, bf16* __restrict__ Wot)
{
    __shared__ bf16 Tl[64][72];
    const int bid = blockIdx.x;
    const int tid = threadIdx.x;

    if (bid < 6144) {
        int gidx = bid * 256 + tid;                   // vec8 group
        int t    = gidx >> 19;
        int off  = (gidx & 0x7FFFF) * 8;
        const float* src = (t == 0) ? q : (t == 1) ? k : v;
        const float4 f0 = *(const float4*)&src[off];
        const float4 f1 = *(const float4*)&src[off + 4];
        bf16x8 p = { (bf16)f0.x, (bf16)f0.y, (bf16)f0.z, (bf16)f0.w,
                     (bf16)f1.x, (bf16)f1.y, (bf16)f1.z, (bf16)f1.w };
        *(bf16x8*)&Xcat[(size_t)gidx * 8] = p;
        return;
    }
    if (bid < 6912) {
        // W[h][k][e] fp32 -> Wqkv[t*1Mi + (h*64+e)*1024 + k]
        int idx = bid - 6144;                         // 768
        int x = idx & 15, z = idx >> 4;               // x: k-tile, z = t*16+h
        int t = z >> 4, h = z & 15;
        const float* inp = ((t == 0) ? Wq : (t == 1) ? Wk : Wv) + (size_t)h * 65536;
        bf16* outp = Wqkv + (size_t)t * 1024 * 1024 + (size_t)h * 65536;
        int r0 = x * 64;
        #pragma unroll
        for (int i = 0; i < 2; i++) {
            int s = tid + i * 256;
            int r = s >> 3, c8 = (s & 7) * 8;
            const float* ap = &inp[(size_t)(r0 + r) * 64 + c8];
            float4 f0 = *(const float4*)ap;
            float4 f1 = *(const float4*)(ap + 4);
            bf16x8 p = { (bf16)f0.x, (bf16)f0.y, (bf16)f0.z, (bf16)f0.w,
                         (bf16)f1.x, (bf16)f1.y, (bf16)f1.z, (bf16)f1.w };
            *(bf16x8*)&Tl[r][c8] = p;
        }
        __syncthreads();
        #pragma unroll
        for (int i = 0; i < 2; i++) {
            int s = tid + i * 256;
            int c = s >> 3, r8 = (s & 7) * 8;
            bf16x8 p;
            #pragma unroll
            for (int j = 0; j < 8; j++) p[j] = Tl[r8 + j][c];
            *(bf16x8*)&outp[(size_t)c * 1024 + r0 + r8] = p;
        }
        return;
    }
    // Wo[h][e][o] fp32 -> Wot[o][h*64+e]
    {
        int idx = bid - 6912;                         // 256
        int y = idx & 15, h = idx >> 4;
        int c0 = y * 64;
        const float* inp = Wo + (size_t)h * 65536;
        bf16* outp = Wot + (size_t)h * 64;
        #pragma unroll
        for (int i = 0; i < 2; i++) {
            int s = tid + i * 256;
            int r = s >> 3, c8 = (s & 7) * 8;
            const float* ap = &inp[(size_t)r * 1024 + c0 + c8];
            float4 f0 = *(const float4*)ap;
            float4 f1 = *(const float4*)(ap + 4);
            bf16x8 p = { (bf16)f0.x, (bf16)f0.y, (bf16)f0.z, (bf16)f0.w,
                         (bf16)f1.x, (bf16)f1.y, (bf16)f1.z, (bf16)f1.w };
            *(bf16x8*)&Tl[r][c8] = p;
        }
        __syncthreads();
        #pragma unroll
        for (int i = 0; i < 2; i++) {
            int s = tid + i * 256;
            int c = s >> 3, r8 = (s & 7) * 8;
            bf16x8 p;
            #pragma unroll
            for (int j = 0; j < 8; j++) p[j] = Tl[r8 + j][c];
            *(bf16x8*)&outp[(size_t)(c0 + c) * 1024 + r8] = p;
        }
    }
}

// ---------------------------------------------------------------------------
// Fused QKV projection GEMM: grid (96, 8); slab = blockIdx.x>>5 in {0,1,2}.
// slab 0 -> Qproj (scaled), slab 1 -> Kproj, slab 2 -> Vt transposed epilogue
// with the 32-block kv PERMUTATION: pos(s) = (s&~31) | ((s>>2)&3)*8 |
// ((s>>4)&1)*4 | (s&3), so attn V-fragments are contiguous b128 reads.
// ---------------------------------------------------------------------------
__global__ __launch_bounds__(256)
void qkv_gemm(const bf16* __restrict__ Xcat, const bf16* __restrict__ Wqkv,
              bf16* __restrict__ Cq, bf16* __restrict__ Ck, bf16* __restrict__ Vt,
              float qscale)
{
    __shared__ bf16 Al[128 * 64];
    __shared__ bf16 Bl[128 * 64];
    const int slab  = blockIdx.x >> 5;
    const int mbase = (blockIdx.x & 31) * 128;
    const int nbase = blockIdx.y * 128;
    const int tid = threadIdx.x;
    const int w = tid >> 6, lane = tid & 63;
    const int lm = lane & 15, q4 = lane >> 4;
    const int wr = (w >> 1) * 64, wc = (w & 1) * 64;
    const int lrow = lane >> 3, lsw = ((lane & 7) ^ lrow) * 8;

    const bf16* A  = Xcat + (size_t)slab * 4096 * 1024;
    const bf16* Bt = Wqkv + (size_t)slab * 1024 * 1024;

    f32x4 acc[4][4] = {};

    for (int k0 = 0; k0 < 1024; k0 += 64) {
        __syncthreads();
        #pragma unroll
        for (int i = 0; i < 4; i++) {
            int c = w * 4 + i;
            gl2lds16(&A [(size_t)(mbase + c * 8 + lrow) * 1024 + k0 + lsw], &Al[c * 512]);
            gl2lds16(&Bt[(size_t)(nbase + c * 8 + lrow) * 1024 + k0 + lsw], &Bl[c * 512]);
        }
        __syncthreads();
        #pragma unroll
        for (int kk2 = 0; kk2 < 2; kk2++) {
            bf16x8 a[4], bfr[4];
            const int g = ((kk2 * 4 + q4) ^ (lm & 7)) * 8;
            #pragma unroll
            for (int i = 0; i < 4; i++) a[i]   = *(const bf16x8*)&Al[(wr + i * 16 + lm) * 64 + g];
            #pragma unroll
            for (int j = 0; j < 4; j++) bfr[j] = *(const bf16x8*)&Bl[(wc + j * 16 + lm) * 64 + g];
            #pragma unroll
            for (int i = 0; i < 4; i++)
                #pragma unroll
                for (int j = 0; j < 4; j++)
                    acc[i][j] = MFMA16(a[i], bfr[j], acc[i][j]);
        }
    }

    if (slab == 2) {
        #pragma unroll
        for (int i = 0; i < 4; i++)
            #pragma unroll
            for (int j = 0; j < 4; j++) {
                int s0  = mbase + wr + i * 16 + q4 * 4;      // kv, multiple of 4
                int col = nbase + wc + j * 16 + lm;          // e
                int sp  = (s0 & ~31) | (((s0 >> 2) & 3) * 8) | (((s0 >> 4) & 1) * 4);
                bf16x4 p = { (bf16)acc[i][j][0], (bf16)acc[i][j][1],
                             (bf16)acc[i][j][2], (bf16)acc[i][j][3] };
                *(bf16x4*)&Vt[(size_t)col * 4096 + sp] = p;
            }
    } else {
        bf16* C = (slab == 0) ? Cq : Ck;
        const float scale = (slab == 0) ? qscale : 1.0f;
        #pragma unroll
        for (int i = 0; i < 4; i++)
            #pragma unroll
            for (int j = 0; j < 4; j++)
                #pragma unroll
                for (int r = 0; r < 4; r++) {
                    int row = mbase + wr + i * 16 + q4 * 4 + r;
                    int col = nbase + wc + j * 16 + lm;
                    C[(size_t)row * 1024 + col] = (bf16)(acc[i][j][r] * scale);
                }
    }
}

// ---------------------------------------------------------------------------
// Output projection, 64x128 (MxN) tiles, grid (64, 8) = 2 blocks/CU.
// out[4096,1024] fp32 = Hd bf16 @ Wot^T
// ---------------------------------------------------------------------------
__global__ __launch_bounds__(256)
void outproj_gemm(const bf16* __restrict__ A, const bf16* __restrict__ Bt,
                  float* __restrict__ C)
{
    __shared__ bf16 Al[64 * 64];
    __shared__ bf16 Bl[128 * 64];
    const int mbase = blockIdx.x * 64;
    const int nbase = blockIdx.y * 128;
    const int tid = threadIdx.x;
    const int w = tid >> 6, lane = tid & 63;
    const int lm = lane & 15, q4 = lane >> 4;
    const int wm = (w >> 1) * 32, wn = (w & 1) * 64;   // 32x64 per wave
    const int lrow = lane >> 3, lsw = ((lane & 7) ^ lrow) * 8;

    f32x4 acc[2][4] = {};

    for (int k0 = 0; k0 < 1024; k0 += 64) {
        __syncthreads();
        #pragma unroll
        for (int i = 0; i < 2; i++) {
            int c = w * 2 + i;                          // 8 chunks of 8 rows
            gl2lds16(&A[(size_t)(mbase + c * 8 + lrow) * 1024 + k0 + lsw], &Al[c * 512]);
        }
        #pragma unroll
        for (int i = 0; i < 4; i++) {
            int c = w * 4 + i;                          // 16 chunks of 8 rows
            gl2lds16(&Bt[(size_t)(nbase + c * 8 + lrow) * 1024 + k0 + lsw], &Bl[c * 512]);
        }
        __syncthreads();
        #pragma unroll
        for (int kk2 = 0; kk2 < 2; kk2++) {
            bf16x8 a[2], bfr[4];
            const int g = ((kk2 * 4 + q4) ^ (lm & 7)) * 8;
            #pragma unroll
            for (int i = 0; i < 2; i++) a[i]   = *(const bf16x8*)&Al[(wm + i * 16 + lm) * 64 + g];
            #pragma unroll
            for (int j = 0; j < 4; j++) bfr[j] = *(const bf16x8*)&Bl[(wn + j * 16 + lm) * 64 + g];
            #pragma unroll
            for (int i = 0; i < 2; i++)
                #pragma unroll
                for (int j = 0; j < 4; j++)
                    acc[i][j] = MFMA16(a[i], bfr[j], acc[i][j]);
        }
    }

    #pragma unroll
    for (int i = 0; i < 2; i++)
        #pragma unroll
        for (int j = 0; j < 4; j++)
            #pragma unroll
            for (int r = 0; r < 4; r++) {
                int row = mbase + wm + i * 16 + q4 * 4 + r;
                int col = nbase + wn + j * 16 + lm;
                C[(size_t)row * 1024 + col] = acc[i][j][r];
            }
}

// ---------------------------------------------------------------------------
// Flash attention, register-P + staged K + permuted V + double buffer.
//   S^T = MFMA(A=K_lds, B=Q_regs)   -> lane holds P for q = lane&15
//   P packed in regs as the PV A-operand (permuted k-order);
//   V pre-permuted in global so V-frags are contiguous b128 LDS reads.
// Round-3 changes (round-2 stagger QUADRUPLED FETCH_SIZE -> dur == bytes/BW;
// root cause of the baseline 70 MB overfetch: default block->XCD round-robin
// puts all 32 (b,h) K/V sets (16 MB) on every XCD's 4 MB L2 -> thrash):
//   * REVERT kv stagger (address-decorrelation killed L2 reuse).
//   * XCD-aware block swizzle (T1): n = qt+32*(b+2h); m = (n%8)*128 + n/8.
//     Each XCD owns 4 complete (b,h) groups = 2 MB K/V, L2-resident; the
//     32 q-blocks of a group sweep kv tiles in lockstep -> one fill each.
//   * keep round-2 wave split (2 q-pairs x 2 kv-halves; 8 ds_read per 18
//     MFMA), Lacc denom-via-MFMA, setprio, LDS merge of kv-halves.
// ---------------------------------------------------------------------------
__global__ __launch_bounds__(256, 4)
void attn_kernel(const bf16* __restrict__ Qp, const bf16* __restrict__ Kp,
                 const bf16* __restrict__ Vt, bf16* __restrict__ Hd)
{
    __shared__ bf16 Kl[2][64 * 64];
    __shared__ bf16 Vl[2][64 * 64];

    // XCD-aware remap (8 XCDs, 1024 blocks, bijective: 1024 = 8*128)
    const int n  = blockIdx.x + 32 * (blockIdx.y + 2 * blockIdx.z);
    const int m  = (n & 7) * 128 + (n >> 3);
    const int qt = m & 31, bh = m >> 5;
    const int b  = bh & 1,  h  = bh >> 1;

    const int qbase = qt * 64;
    const int tid  = threadIdx.x;
    const int w    = tid >> 6, lane = tid & 63;
    const int p    = w & 1;          // q-pair: rows [p*32, p*32+32)
    const int kvh  = w >> 1;         // kv half of each 64-wide tile
    const int lm   = lane & 15, q4 = lane >> 4;
    const int lrow = lane >> 3, lsw = ((lane & 7) ^ lrow) * 8;

    const bf16* Qh = Qp + (size_t)(b * 2048 + qbase + p * 32) * 1024 + h * 64;
    const bf16* Kh = Kp + (size_t)(b * 2048) * 1024 + h * 64;
    const bf16* Vh = Vt + (size_t)(h * 64) * 4096 + b * 2048;

    // Q fragments (loop-invariant), B-operand layout: n=lm, k=q4*8+j
    bf16x8 Qf[2][2];
    #pragma unroll
    for (int i = 0; i < 2; i++)
        #pragma unroll
        for (int kk2 = 0; kk2 < 2; kk2++)
            Qf[i][kk2] = *(const bf16x8*)&Qh[(size_t)(i * 16 + lm) * 1024 + kk2 * 32 + q4 * 8];

    const bf16 one = (bf16)1.0f;
    const bf16x8 ones = { one, one, one, one, one, one, one, one };

    f32x4 O[2][4] = {};
    f32x4 Lacc[2] = {};   // row-sums of P (softmax denom), same row layout as O

    // stage kv-tile kt into buffer d (K rows=kv, V rows=e; identical pattern)
    auto stage = [&](int kt, int d) {
        #pragma unroll
        for (int i = 0; i < 2; i++) {
            int c = w * 2 + i;                           // 8 chunks of 8 rows
            gl2lds16(&Kh[(size_t)(kt * 64 + c * 8 + lrow) * 1024 + lsw], &Kl[d][c * 512]);
            gl2lds16(&Vh[(size_t)(c * 8 + lrow) * 4096 + kt * 64 + lsw], &Vl[d][c * 512]);
        }
    };

    stage(0, 0);

    for (int it = 0; it < 32; it++) {
        __syncthreads();                                 // buf[it&1] ready
        if (it < 31) stage(it + 1, (it + 1) & 1);        // overlap with compute
        const bf16* Kd = &Kl[it & 1][0];
        const bf16* Vd = &Vl[it & 1][0];

        // S^T for this wave's kv-half: ctp in {kvh*2, kvh*2+1}
        f32x4 St[2][2] = {};
        __builtin_amdgcn_s_setprio(1);
        #pragma unroll
        for (int c2 = 0; c2 < 2; c2++) {
            const int ctp = kvh * 2 + c2;
            #pragma unroll
            for (int kk2 = 0; kk2 < 2; kk2++) {
                const int g = ((kk2 * 4 + q4) ^ (lm & 7)) * 8;
                bf16x8 kf = *(const bf16x8*)&Kd[(ctp * 16 + lm) * 64 + g];
                #pragma unroll
                for (int i = 0; i < 2; i++)
                    St[i][c2] = MFMA16(kf, Qf[i][kk2], St[i][c2]);
            }
        }
        __builtin_amdgcn_s_setprio(0);

        // P = exp2(S^T) packed into A-slots for this kv-32 chunk (kk4 = kvh)
        bf16x8 Pf[2];
        #pragma unroll
        for (int i = 0; i < 2; i++)
            #pragma unroll
            for (int j = 0; j < 8; j++)
                Pf[i][j] = (bf16)__builtin_amdgcn_exp2f(St[i][j >> 2][j & 3]);

        __builtin_amdgcn_s_setprio(1);
        #pragma unroll
        for (int i = 0; i < 2; i++) Lacc[i] = MFMA16(Pf[i], ones, Lacc[i]);
        const int gv = ((kvh * 4 + q4) ^ (lm & 7)) * 8;
        #pragma unroll
        for (int et = 0; et < 4; et++) {
            bf16x8 vf = *(const bf16x8*)&Vd[(et * 16 + lm) * 64 + gv];
            #pragma unroll
            for (int i = 0; i < 2; i++)
                O[i][et] = MFMA16(Pf[i], vf, O[i][et]);
        }
        __builtin_amdgcn_s_setprio(0);
    }

    // ---- merge the two kv-halves via LDS (reuse Kl/Vl; 16 KB + 256 B) ----
    __syncthreads();                       // last tile's reads done
    float* Ol = (float*)&Kl[0][0];         // [p][32 rows][64 cols] f32
    float* Ll = (float*)&Vl[0][0];         // [p][32 rows] f32
    if (kvh == 1) {
        #pragma unroll
        for (int i = 0; i < 2; i++)
            #pragma unroll
            for (int et = 0; et < 4; et++)
                #pragma unroll
                for (int r = 0; r < 4; r++)
                    Ol[p * 2048 + (i * 16 + q4 * 4 + r) * 64 + et * 16 + lm] = O[i][et][r];
        if (lm == 0) {
            #pragma unroll
            for (int i = 0; i < 2; i++)
                #pragma unroll
                for (int r = 0; r < 4; r++)
                    Ll[p * 32 + i * 16 + q4 * 4 + r] = Lacc[i][r];
        }
    }
    __syncthreads();
    if (kvh == 0) {
        #pragma unroll
        for (int i = 0; i < 2; i++) {
            float rl[4];
            #pragma unroll
            for (int r = 0; r < 4; r++)
                rl[r] = 1.0f / (Lacc[i][r] + Ll[p * 32 + i * 16 + q4 * 4 + r]);
            #pragma unroll
            for (int et = 0; et < 4; et++)
                #pragma unroll
                for (int r = 0; r < 4; r++) {
                    float o = O[i][et][r] +
                              Ol[p * 2048 + (i * 16 + q4 * 4 + r) * 64 + et * 16 + lm];
                    int row = b * 2048 + qbase + p * 32 + i * 16 + q4 * 4 + r;
                    Hd[(size_t)row * 1024 + h * 64 + et * 16 + lm] = (bf16)(o * rl[r]);
                }
        }
    }
}

extern "C" void kernel_launch(void* const* d_in, const int* in_sizes, int n_in,
                              void* d_out, int out_size, void* d_ws, size_t ws_size,
                              hipStream_t stream)
{
    const float* q  = (const float*)d_in[0];
    const float* k  = (const float*)d_in[1];
    const float* v  = (const float*)d_in[2];
    const float* Wq = (const float*)d_in[3];
    const float* Wk = (const float*)d_in[4];
    const float* Wv = (const float*)d_in[5];
    const float* Wo = (const float*)d_in[6];
    float* out = (float*)d_out;

    // ws (bf16 elems, Mi = 1024*1024; 24Mi = 48 MB):
    //  [ 0, 4) qb -> Hd (attn out; qb dead after qkv_gemm)   [ 4, 8) kb
    //  [ 8,12) vb    [12,15) Wqkv   [15,16) Wot   [16,20) Qproj   [20,24) Kproj
    // Vt (bf16, 8 MB, kv-permuted) lives in d_out (16 MB fp32), overwritten
    // by outproj at the very end.
    const size_t Mi = 1024 * 1024;
    bf16* Xcat  = (bf16*)d_ws;
    bf16* Hd    = Xcat;                   // alias qb
    bf16* Wqkv  = Xcat + 12 * Mi;
    bf16* Wot   = Xcat + 15 * Mi;
    bf16* Qproj = Xcat + 16 * Mi;
    bf16* Kproj = Xcat + 20 * Mi;
    bf16* Vtb   = (bf16*)d_out;

    const float qscale = 0.125f * 1.4426950408889634f;  // 1/sqrt(64) * log2(e)

    prep_kernel<<<7168, 256, 0, stream>>>(q, k, v, Wq, Wk, Wv, Wo, Xcat, Wqkv, Wot);
    qkv_gemm<<<dim3(96, 8), 256, 0, stream>>>(Xcat, Wqkv, Qproj, Kproj, Vtb, qscale);
    attn_kernel<<<dim3(32, 2, 16), 256, 0, stream>>>(Qproj, Kproj, Vtb, Hd);
    outproj_gemm<<<dim3(64, 8), 256, 0, stream>>>(Hd, Wot, out);
}

// Round 4
// 203.946 us; speedup vs baseline: 1.2038x; 1.0346x over previous
//
#include <hip/hip_runtime.h>
#include <hip/hip_bf16.h>

typedef __bf16 bf16;
typedef __bf16 bf16x8 __attribute__((ext_vector_type(8)));
typedef __bf16 bf16x4 __attribute__((ext_vector_type(4)));
typedef float  f32x4  __attribute__((ext_vector_type(4)));

#define MFMA16(a,b,c) __builtin_amdgcn_mfma_f32_16x16x32_bf16(a, b, c, 0, 0, 0)

// async global->LDS, 16B per lane; lds dst is wave-uniform base + lane*16
__device__ __forceinline__ void gl2lds16(const bf16* g, bf16* l) {
    __builtin_amdgcn_global_load_lds(
        (__attribute__((address_space(1))) void*)g,
        (__attribute__((address_space(3))) void*)l, 16, 0, 0);
}

// ---------------------------------------------------------------------------
// Fused prep: blocks [0,6144) fp32->bf16 cvt of q|k|v; [6144,6912) Wq/Wk/Wv
// transpose; [6912,7168) Wo transpose.
// ---------------------------------------------------------------------------
__global__ __launch_bounds__(256)
void prep_kernel(const float* __restrict__ q, const float* __restrict__ k,
                 const float* __restrict__ v, const float* __restrict__ Wq,
                 const float* __restrict__ Wk, const float* __restrict__ Wv,
                 const float* __restrict__ Wo, bf16* __restrict__ Xcat,
                 bf16* __restrict__ Wqkv, bf16* __restrict__ Wot)
{
    __shared__ bf16 Tl[64][72];
    const int bid = blockIdx.x;
    const int tid = threadIdx.x;

    if (bid < 6144) {
        int gidx = bid * 256 + tid;                   // vec8 group
        int t    = gidx >> 19;
        int off  = (gidx & 0x7FFFF) * 8;
        const float* src = (t == 0) ? q : (t == 1) ? k : v;
        const float4 f0 = *(const float4*)&src[off];
        const float4 f1 = *(const float4*)&src[off + 4];
        bf16x8 p = { (bf16)f0.x, (bf16)f0.y, (bf16)f0.z, (bf16)f0.w,
                     (bf16)f1.x, (bf16)f1.y, (bf16)f1.z, (bf16)f1.w };
        *(bf16x8*)&Xcat[(size_t)gidx * 8] = p;
        return;
    }
    if (bid < 6912) {
        // W[h][k][e] fp32 -> Wqkv[t*1Mi + (h*64+e)*1024 + k]
        int idx = bid - 6144;                         // 768
        int x = idx & 15, z = idx >> 4;               // x: k-tile, z = t*16+h
        int t = z >> 4, h = z & 15;
        const float* inp = ((t == 0) ? Wq : (t == 1) ? Wk : Wv) + (size_t)h * 65536;
        bf16* outp = Wqkv + (size_t)t * 1024 * 1024 + (size_t)h * 65536;
        int r0 = x * 64;
        #pragma unroll
        for (int i = 0; i < 2; i++) {
            int s = tid + i * 256;
            int r = s >> 3, c8 = (s & 7) * 8;
            const float* ap = &inp[(size_t)(r0 + r) * 64 + c8];
            float4 f0 = *(const float4*)ap;
            float4 f1 = *(const float4*)(ap + 4);
            bf16x8 p = { (bf16)f0.x, (bf16)f0.y, (bf16)f0.z, (bf16)f0.w,
                         (bf16)f1.x, (bf16)f1.y, (bf16)f1.z, (bf16)f1.w };
            *(bf16x8*)&Tl[r][c8] = p;
        }
        __syncthreads();
        #pragma unroll
        for (int i = 0; i < 2; i++) {
            int s = tid + i * 256;
            int c = s >> 3, r8 = (s & 7) * 8;
            bf16x8 p;
            #pragma unroll
            for (int j = 0; j < 8; j++) p[j] = Tl[r8 + j][c];
            *(bf16x8*)&outp[(size_t)c * 1024 + r0 + r8] = p;
        }
        return;
    }
    // Wo[h][e][o] fp32 -> Wot[o][h*64+e]
    {
        int idx = bid - 6912;                         // 256
        int y = idx & 15, h = idx >> 4;
        int c0 = y * 64;
        const float* inp = Wo + (size_t)h * 65536;
        bf16* outp = Wot + (size_t)h * 64;
        #pragma unroll
        for (int i = 0; i < 2; i++) {
            int s = tid + i * 256;
            int r = s >> 3, c8 = (s & 7) * 8;
            const float* ap = &inp[(size_t)r * 1024 + c0 + c8];
            float4 f0 = *(const float4*)ap;
            float4 f1 = *(const float4*)(ap + 4);
            bf16x8 p = { (bf16)f0.x, (bf16)f0.y, (bf16)f0.z, (bf16)f0.w,
                         (bf16)f1.x, (bf16)f1.y, (bf16)f1.z, (bf16)f1.w };
            *(bf16x8*)&Tl[r][c8] = p;
        }
        __syncthreads();
        #pragma unroll
        for (int i = 0; i < 2; i++) {
            int s = tid + i * 256;
            int c = s >> 3, r8 = (s & 7) * 8;
            bf16x8 p;
            #pragma unroll
            for (int j = 0; j < 8; j++) p[j] = Tl[r8 + j][c];
            *(bf16x8*)&outp[(size_t)(c0 + c) * 1024 + r8] = p;
        }
    }
}

// ---------------------------------------------------------------------------
// Fused QKV projection GEMM: grid (96, 8); slab = blockIdx.x>>5 in {0,1,2}.
// slab 0 -> Qproj (scaled), slab 1 -> Kproj, slab 2 -> Vt transposed epilogue
// with the 32-block kv PERMUTATION: pos(s) = (s&~31) | ((s>>2)&3)*8 |
// ((s>>4)&1)*4 | (s&3), so attn V-fragments are contiguous b128 reads.
// Round-4: double-buffered LDS + stage(t+1)-before-compute(t) + one barrier
// per K-tile (the attn-kernel schedule). Round-3 counters showed the
// single-buffered loop fully serialized load and compute (all pipes ~20%,
// 474 TF). LDS 64 KB -> 2 blocks/CU; in-block overlap replaces the 3rd block.
// ---------------------------------------------------------------------------
__global__ __launch_bounds__(256)
void qkv_gemm(const bf16* __restrict__ Xcat, const bf16* __restrict__ Wqkv,
              bf16* __restrict__ Cq, bf16* __restrict__ Ck, bf16* __restrict__ Vt,
              float qscale)
{
    __shared__ bf16 Al[2][128 * 64];
    __shared__ bf16 Bl[2][128 * 64];
    const int slab  = blockIdx.x >> 5;
    const int mbase = (blockIdx.x & 31) * 128;
    const int nbase = blockIdx.y * 128;
    const int tid = threadIdx.x;
    const int w = tid >> 6, lane = tid & 63;
    const int lm = lane & 15, q4 = lane >> 4;
    const int wr = (w >> 1) * 64, wc = (w & 1) * 64;
    const int lrow = lane >> 3, lsw = ((lane & 7) ^ lrow) * 8;

    const bf16* A  = Xcat + (size_t)slab * 4096 * 1024;
    const bf16* Bt = Wqkv + (size_t)slab * 1024 * 1024;

    f32x4 acc[4][4] = {};

    auto stage = [&](int k0, int d) {
        #pragma unroll
        for (int i = 0; i < 4; i++) {
            int c = w * 4 + i;
            gl2lds16(&A [(size_t)(mbase + c * 8 + lrow) * 1024 + k0 + lsw], &Al[d][c * 512]);
            gl2lds16(&Bt[(size_t)(nbase + c * 8 + lrow) * 1024 + k0 + lsw], &Bl[d][c * 512]);
        }
    };

    stage(0, 0);

    for (int t = 0; t < 16; t++) {
        __syncthreads();                      // buf[t&1] ready (loads had a full
        if (t < 15) stage((t + 1) * 64, (t + 1) & 1);   // compute phase to land)
        const bf16* Ad = &Al[t & 1][0];
        const bf16* Bd = &Bl[t & 1][0];
        __builtin_amdgcn_s_setprio(1);
        #pragma unroll
        for (int kk2 = 0; kk2 < 2; kk2++) {
            bf16x8 a[4], bfr[4];
            const int g = ((kk2 * 4 + q4) ^ (lm & 7)) * 8;
            #pragma unroll
            for (int i = 0; i < 4; i++) a[i]   = *(const bf16x8*)&Ad[(wr + i * 16 + lm) * 64 + g];
            #pragma unroll
            for (int j = 0; j < 4; j++) bfr[j] = *(const bf16x8*)&Bd[(wc + j * 16 + lm) * 64 + g];
            #pragma unroll
            for (int i = 0; i < 4; i++)
                #pragma unroll
                for (int j = 0; j < 4; j++)
                    acc[i][j] = MFMA16(a[i], bfr[j], acc[i][j]);
        }
        __builtin_amdgcn_s_setprio(0);
    }

    if (slab == 2) {
        #pragma unroll
        for (int i = 0; i < 4; i++)
            #pragma unroll
            for (int j = 0; j < 4; j++) {
                int s0  = mbase + wr + i * 16 + q4 * 4;      // kv, multiple of 4
                int col = nbase + wc + j * 16 + lm;          // e
                int sp  = (s0 & ~31) | (((s0 >> 2) & 3) * 8) | (((s0 >> 4) & 1) * 4);
                bf16x4 p = { (bf16)acc[i][j][0], (bf16)acc[i][j][1],
                             (bf16)acc[i][j][2], (bf16)acc[i][j][3] };
                *(bf16x4*)&Vt[(size_t)col * 4096 + sp] = p;
            }
    } else {
        bf16* C = (slab == 0) ? Cq : Ck;
        const float scale = (slab == 0) ? qscale : 1.0f;
        #pragma unroll
        for (int i = 0; i < 4; i++)
            #pragma unroll
            for (int j = 0; j < 4; j++)
                #pragma unroll
                for (int r = 0; r < 4; r++) {
                    int row = mbase + wr + i * 16 + q4 * 4 + r;
                    int col = nbase + wc + j * 16 + lm;
                    C[(size_t)row * 1024 + col] = (bf16)(acc[i][j][r] * scale);
                }
    }
}

// ---------------------------------------------------------------------------
// Output projection, 64x128 (MxN) tiles, grid (64, 8).
// out[4096,1024] fp32 = Hd bf16 @ Wot^T
// Round-4: same double-buffer + stage-before-compute schedule as qkv_gemm.
// LDS 48 KB -> still 3 blocks/CU.
// ---------------------------------------------------------------------------
__global__ __launch_bounds__(256)
void outproj_gemm(const bf16* __restrict__ A, const bf16* __restrict__ Bt,
                  float* __restrict__ C)
{
    __shared__ bf16 Al[2][64 * 64];
    __shared__ bf16 Bl[2][128 * 64];
    const int mbase = blockIdx.x * 64;
    const int nbase = blockIdx.y * 128;
    const int tid = threadIdx.x;
    const int w = tid >> 6, lane = tid & 63;
    const int lm = lane & 15, q4 = lane >> 4;
    const int wm = (w >> 1) * 32, wn = (w & 1) * 64;   // 32x64 per wave
    const int lrow = lane >> 3, lsw = ((lane & 7) ^ lrow) * 8;

    f32x4 acc[2][4] = {};

    auto stage = [&](int k0, int d) {
        #pragma unroll
        for (int i = 0; i < 2; i++) {
            int c = w * 2 + i;                          // 8 chunks of 8 rows
            gl2lds16(&A[(size_t)(mbase + c * 8 + lrow) * 1024 + k0 + lsw], &Al[d][c * 512]);
        }
        #pragma unroll
        for (int i = 0; i < 4; i++) {
            int c = w * 4 + i;                          // 16 chunks of 8 rows
            gl2lds16(&Bt[(size_t)(nbase + c * 8 + lrow) * 1024 + k0 + lsw], &Bl[d][c * 512]);
        }
    };

    stage(0, 0);

    for (int t = 0; t < 16; t++) {
        __syncthreads();
        if (t < 15) stage((t + 1) * 64, (t + 1) & 1);
        const bf16* Ad = &Al[t & 1][0];
        const bf16* Bd = &Bl[t & 1][0];
        __builtin_amdgcn_s_setprio(1);
        #pragma unroll
        for (int kk2 = 0; kk2 < 2; kk2++) {
            bf16x8 a[2], bfr[4];
            const int g = ((kk2 * 4 + q4) ^ (lm & 7)) * 8;
            #pragma unroll
            for (int i = 0; i < 2; i++) a[i]   = *(const bf16x8*)&Ad[(wm + i * 16 + lm) * 64 + g];
            #pragma unroll
            for (int j = 0; j < 4; j++) bfr[j] = *(const bf16x8*)&Bd[(wn + j * 16 + lm) * 64 + g];
            #pragma unroll
            for (int i = 0; i < 2; i++)
                #pragma unroll
                for (int j = 0; j < 4; j++)
                    acc[i][j] = MFMA16(a[i], bfr[j], acc[i][j]);
        }
        __builtin_amdgcn_s_setprio(0);
    }

    #pragma unroll
    for (int i = 0; i < 2; i++)
        #pragma unroll
        for (int j = 0; j < 4; j++)
            #pragma unroll
            for (int r = 0; r < 4; r++) {
                int row = mbase + wm + i * 16 + q4 * 4 + r;
                int col = nbase + wn + j * 16 + lm;
                C[(size_t)row * 1024 + col] = acc[i][j][r];
            }
}

// ---------------------------------------------------------------------------
// Flash attention, register-P + staged K + permuted V + double buffer.
//   S^T = MFMA(A=K_lds, B=Q_regs)   -> lane holds P for q = lane&15
//   P packed in regs as the PV A-operand (permuted k-order);
//   V pre-permuted in global so V-frags are contiguous b128 LDS reads.
//   * XCD-aware block swizzle (T1): each XCD owns 4 complete (b,h) groups
//     = 2 MB K/V, L2-resident (round-3: FETCH 266 -> ~70 MB, attn out of
//     top-5). No kv stagger (address-decorrelation kills L2 reuse).
//   * 4 waves/block = 2 q-pairs x 2 kv-halves (8 ds_read per 18 MFMA).
//   * Lacc denom-via-MFMA, setprio, LDS merge of kv-halves.
// ---------------------------------------------------------------------------
__global__ __launch_bounds__(256, 4)
void attn_kernel(const bf16* __restrict__ Qp, const bf16* __restrict__ Kp,
                 const bf16* __restrict__ Vt, bf16* __restrict__ Hd)
{
    __shared__ bf16 Kl[2][64 * 64];
    __shared__ bf16 Vl[2][64 * 64];

    // XCD-aware remap (8 XCDs, 1024 blocks, bijective: 1024 = 8*128)
    const int n  = blockIdx.x + 32 * (blockIdx.y + 2 * blockIdx.z);
    const int m  = (n & 7) * 128 + (n >> 3);
    const int qt = m & 31, bh = m >> 5;
    const int b  = bh & 1,  h  = bh >> 1;

    const int qbase = qt * 64;
    const int tid  = threadIdx.x;
    const int w    = tid >> 6, lane = tid & 63;
    const int p    = w & 1;          // q-pair: rows [p*32, p*32+32)
    const int kvh  = w >> 1;         // kv half of each 64-wide tile
    const int lm   = lane & 15, q4 = lane >> 4;
    const int lrow = lane >> 3, lsw = ((lane & 7) ^ lrow) * 8;

    const bf16* Qh = Qp + (size_t)(b * 2048 + qbase + p * 32) * 1024 + h * 64;
    const bf16* Kh = Kp + (size_t)(b * 2048) * 1024 + h * 64;
    const bf16* Vh = Vt + (size_t)(h * 64) * 4096 + b * 2048;

    // Q fragments (loop-invariant), B-operand layout: n=lm, k=q4*8+j
    bf16x8 Qf[2][2];
    #pragma unroll
    for (int i = 0; i < 2; i++)
        #pragma unroll
        for (int kk2 = 0; kk2 < 2; kk2++)
            Qf[i][kk2] = *(const bf16x8*)&Qh[(size_t)(i * 16 + lm) * 1024 + kk2 * 32 + q4 * 8];

    const bf16 one = (bf16)1.0f;
    const bf16x8 ones = { one, one, one, one, one, one, one, one };

    f32x4 O[2][4] = {};
    f32x4 Lacc[2] = {};   // row-sums of P (softmax denom), same row layout as O

    // stage kv-tile kt into buffer d (K rows=kv, V rows=e; identical pattern)
    auto stage = [&](int kt, int d) {
        #pragma unroll
        for (int i = 0; i < 2; i++) {
            int c = w * 2 + i;                           // 8 chunks of 8 rows
            gl2lds16(&Kh[(size_t)(kt * 64 + c * 8 + lrow) * 1024 + lsw], &Kl[d][c * 512]);
            gl2lds16(&Vh[(size_t)(c * 8 + lrow) * 4096 + kt * 64 + lsw], &Vl[d][c * 512]);
        }
    };

    stage(0, 0);

    for (int it = 0; it < 32; it++) {
        __syncthreads();                                 // buf[it&1] ready
        if (it < 31) stage(it + 1, (it + 1) & 1);        // overlap with compute
        const bf16* Kd = &Kl[it & 1][0];
        const bf16* Vd = &Vl[it & 1][0];

        // S^T for this wave's kv-half: ctp in {kvh*2, kvh*2+1}
        f32x4 St[2][2] = {};
        __builtin_amdgcn_s_setprio(1);
        #pragma unroll
        for (int c2 = 0; c2 < 2; c2++) {
            const int ctp = kvh * 2 + c2;
            #pragma unroll
            for (int kk2 = 0; kk2 < 2; kk2++) {
                const int g = ((kk2 * 4 + q4) ^ (lm & 7)) * 8;
                bf16x8 kf = *(const bf16x8*)&Kd[(ctp * 16 + lm) * 64 + g];
                #pragma unroll
                for (int i = 0; i < 2; i++)
                    St[i][c2] = MFMA16(kf, Qf[i][kk2], St[i][c2]);
            }
        }
        __builtin_amdgcn_s_setprio(0);

        // P = exp2(S^T) packed into A-slots for this kv-32 chunk (kk4 = kvh)
        bf16x8 Pf[2];
        #pragma unroll
        for (int i = 0; i < 2; i++)
            #pragma unroll
            for (int j = 0; j < 8; j++)
                Pf[i][j] = (bf16)__builtin_amdgcn_exp2f(St[i][j >> 2][j & 3]);

        __builtin_amdgcn_s_setprio(1);
        #pragma unroll
        for (int i = 0; i < 2; i++) Lacc[i] = MFMA16(Pf[i], ones, Lacc[i]);
        const int gv = ((kvh * 4 + q4) ^ (lm & 7)) * 8;
        #pragma unroll
        for (int et = 0; et < 4; et++) {
            bf16x8 vf = *(const bf16x8*)&Vd[(et * 16 + lm) * 64 + gv];
            #pragma unroll
            for (int i = 0; i < 2; i++)
                O[i][et] = MFMA16(Pf[i], vf, O[i][et]);
        }
        __builtin_amdgcn_s_setprio(0);
    }

    // ---- merge the two kv-halves via LDS (reuse Kl/Vl; 16 KB + 256 B) ----
    __syncthreads();                       // last tile's reads done
    float* Ol = (float*)&Kl[0][0];         // [p][32 rows][64 cols] f32
    float* Ll = (float*)&Vl[0][0];         // [p][32 rows] f32
    if (kvh == 1) {
        #pragma unroll
        for (int i = 0; i < 2; i++)
            #pragma unroll
            for (int et = 0; et < 4; et++)
                #pragma unroll
                for (int r = 0; r < 4; r++)
                    Ol[p * 2048 + (i * 16 + q4 * 4 + r) * 64 + et * 16 + lm] = O[i][et][r];
        if (lm == 0) {
            #pragma unroll
            for (int i = 0; i < 2; i++)
                #pragma unroll
                for (int r = 0; r < 4; r++)
                    Ll[p * 32 + i * 16 + q4 * 4 + r] = Lacc[i][r];
        }
    }
    __syncthreads();
    if (kvh == 0) {
        #pragma unroll
        for (int i = 0; i < 2; i++) {
            float rl[4];
            #pragma unroll
            for (int r = 0; r < 4; r++)
                rl[r] = 1.0f / (Lacc[i][r] + Ll[p * 32 + i * 16 + q4 * 4 + r]);
            #pragma unroll
            for (int et = 0; et < 4; et++)
                #pragma unroll
                for (int r = 0; r < 4; r++) {
                    float o = O[i][et][r] +
                              Ol[p * 2048 + (i * 16 + q4 * 4 + r) * 64 + et * 16 + lm];
                    int row = b * 2048 + qbase + p * 32 + i * 16 + q4 * 4 + r;
                    Hd[(size_t)row * 1024 + h * 64 + et * 16 + lm] = (bf16)(o * rl[r]);
                }
        }
    }
}

extern "C" void kernel_launch(void* const* d_in, const int* in_sizes, int n_in,
                              void* d_out, int out_size, void* d_ws, size_t ws_size,
                              hipStream_t stream)
{
    const float* q  = (const float*)d_in[0];
    const float* k  = (const float*)d_in[1];
    const float* v  = (const float*)d_in[2];
    const float* Wq = (const float*)d_in[3];
    const float* Wk = (const float*)d_in[4];
    const float* Wv = (const float*)d_in[5];
    const float* Wo = (const float*)d_in[6];
    float* out = (float*)d_out;

    // ws (bf16 elems, Mi = 1024*1024; 24Mi = 48 MB):
    //  [ 0, 4) qb -> Hd (attn out; qb dead after qkv_gemm)   [ 4, 8) kb
    //  [ 8,12) vb    [12,15) Wqkv   [15,16) Wot   [16,20) Qproj   [20,24) Kproj
    // Vt (bf16, 8 MB, kv-permuted) lives in d_out (16 MB fp32), overwritten
    // by outproj at the very end.
    const size_t Mi = 1024 * 1024;
    bf16* Xcat  = (bf16*)d_ws;
    bf16* Hd    = Xcat;                   // alias qb
    bf16* Wqkv  = Xcat + 12 * Mi;
    bf16* Wot   = Xcat + 15 * Mi;
    bf16* Qproj = Xcat + 16 * Mi;
    bf16* Kproj = Xcat + 20 * Mi;
    bf16* Vtb   = (bf16*)d_out;

    const float qscale = 0.125f * 1.4426950408889634f;  // 1/sqrt(64) * log2(e)

    prep_kernel<<<7168, 256, 0, stream>>>(q, k, v, Wq, Wk, Wv, Wo, Xcat, Wqkv, Wot);
    qkv_gemm<<<dim3(96, 8), 256, 0, stream>>>(Xcat, Wqkv, Qproj, Kproj, Vtb, qscale);
    attn_kernel<<<dim3(32, 2, 16), 256, 0, stream>>>(Qproj, Kproj, Vtb, Hd);
    outproj_gemm<<<dim3(64, 8), 256, 0, stream>>>(Hd, Wot, out);
}

// Round 5
// 202.204 us; speedup vs baseline: 1.2142x; 1.0086x over previous
//
#include <hip/hip_runtime.h>
#include <hip/hip_bf16.h>

typedef __bf16 bf16;
typedef __bf16 bf16x8 __attribute__((ext_vector_type(8)));
typedef __bf16 bf16x4 __attribute__((ext_vector_type(4)));
typedef float  f32x4  __attribute__((ext_vector_type(4)));

#define MFMA16(a,b,c) __builtin_amdgcn_mfma_f32_16x16x32_bf16(a, b, c, 0, 0, 0)

// async global->LDS, 16B per lane; lds dst is wave-uniform base + lane*16
__device__ __forceinline__ void gl2lds16(const bf16* g, bf16* l) {
    __builtin_amdgcn_global_load_lds(
        (__attribute__((address_space(1))) void*)g,
        (__attribute__((address_space(3))) void*)l, 16, 0, 0);
}

// ---------------------------------------------------------------------------
// Fused prep: blocks [0,6144) fp32->bf16 cvt of q|k|v; [6144,6912) Wq/Wk/Wv
// transpose; [6912,7168) Wo transpose.
// ---------------------------------------------------------------------------
__global__ __launch_bounds__(256)
void prep_kernel(const float* __restrict__ q, const float* __restrict__ k,
                 const float* __restrict__ v, const float* __restrict__ Wq,
                 const float* __restrict__ Wk, const float* __restrict__ Wv,
                 const float* __restrict__ Wo, bf16* __restrict__ Xcat,
                 bf16* __restrict__ Wqkv, bf16* __restrict__ Wot)
{
    __shared__ bf16 Tl[64][72];
    const int bid = blockIdx.x;
    const int tid = threadIdx.x;

    if (bid < 6144) {
        int gidx = bid * 256 + tid;                   // vec8 group
        int t    = gidx >> 19;
        int off  = (gidx & 0x7FFFF) * 8;
        const float* src = (t == 0) ? q : (t == 1) ? k : v;
        const float4 f0 = *(const float4*)&src[off];
        const float4 f1 = *(const float4*)&src[off + 4];
        bf16x8 p = { (bf16)f0.x, (bf16)f0.y, (bf16)f0.z, (bf16)f0.w,
                     (bf16)f1.x, (bf16)f1.y, (bf16)f1.z, (bf16)f1.w };
        *(bf16x8*)&Xcat[(size_t)gidx * 8] = p;
        return;
    }
    if (bid < 6912) {
        // W[h][k][e] fp32 -> Wqkv[t*1Mi + (h*64+e)*1024 + k]
        int idx = bid - 6144;                         // 768
        int x = idx & 15, z = idx >> 4;               // x: k-tile, z = t*16+h
        int t = z >> 4, h = z & 15;
        const float* inp = ((t == 0) ? Wq : (t == 1) ? Wk : Wv) + (size_t)h * 65536;
        bf16* outp = Wqkv + (size_t)t * 1024 * 1024 + (size_t)h * 65536;
        int r0 = x * 64;
        #pragma unroll
        for (int i = 0; i < 2; i++) {
            int s = tid + i * 256;
            int r = s >> 3, c8 = (s & 7) * 8;
            const float* ap = &inp[(size_t)(r0 + r) * 64 + c8];
            float4 f0 = *(const float4*)ap;
            float4 f1 = *(const float4*)(ap + 4);
            bf16x8 p = { (bf16)f0.x, (bf16)f0.y, (bf16)f0.z, (bf16)f0.w,
                         (bf16)f1.x, (bf16)f1.y, (bf16)f1.z, (bf16)f1.w };
            *(bf16x8*)&Tl[r][c8] = p;
        }
        __syncthreads();
        #pragma unroll
        for (int i = 0; i < 2; i++) {
            int s = tid + i * 256;
            int c = s >> 3, r8 = (s & 7) * 8;
            bf16x8 p;
            #pragma unroll
            for (int j = 0; j < 8; j++) p[j] = Tl[r8 + j][c];
            *(bf16x8*)&outp[(size_t)c * 1024 + r0 + r8] = p;
        }
        return;
    }
    // Wo[h][e][o] fp32 -> Wot[o][h*64+e]
    {
        int idx = bid - 6912;                         // 256
        int y = idx & 15, h = idx >> 4;
        int c0 = y * 64;
        const float* inp = Wo + (size_t)h * 65536;
        bf16* outp = Wot + (size_t)h * 64;
        #pragma unroll
        for (int i = 0; i < 2; i++) {
            int s = tid + i * 256;
            int r = s >> 3, c8 = (s & 7) * 8;
            const float* ap = &inp[(size_t)r * 1024 + c0 + c8];
            float4 f0 = *(const float4*)ap;
            float4 f1 = *(const float4*)(ap + 4);
            bf16x8 p = { (bf16)f0.x, (bf16)f0.y, (bf16)f0.z, (bf16)f0.w,
                         (bf16)f1.x, (bf16)f1.y, (bf16)f1.z, (bf16)f1.w };
            *(bf16x8*)&Tl[r][c8] = p;
        }
        __syncthreads();
        #pragma unroll
        for (int i = 0; i < 2; i++) {
            int s = tid + i * 256;
            int c = s >> 3, r8 = (s & 7) * 8;
            bf16x8 p;
            #pragma unroll
            for (int j = 0; j < 8; j++) p[j] = Tl[r8 + j][c];
            *(bf16x8*)&outp[(size_t)(c0 + c) * 1024 + r8] = p;
        }
    }
}

// ---------------------------------------------------------------------------
// Fused QKV projection GEMM: grid (96, 8); slab = blockIdx.x>>5 in {0,1,2}.
// slab 0 -> Qproj (scaled), slab 1 -> Kproj, slab 2 -> Vt transposed epilogue
// with the 32-block kv PERMUTATION: pos(s) = (s&~31) | ((s>>2)&3)*8 |
// ((s>>4)&1)*4 | (s&3), so attn V-fragments are contiguous b128 reads.
// Double-buffered LDS + stage(t+1)-before-compute(t) + one barrier per K-tile.
// ---------------------------------------------------------------------------
__global__ __launch_bounds__(256)
void qkv_gemm(const bf16* __restrict__ Xcat, const bf16* __restrict__ Wqkv,
              bf16* __restrict__ Cq, bf16* __restrict__ Ck, bf16* __restrict__ Vt,
              float qscale)
{
    __shared__ bf16 Al[2][128 * 64];
    __shared__ bf16 Bl[2][128 * 64];
    const int slab  = blockIdx.x >> 5;
    const int mbase = (blockIdx.x & 31) * 128;
    const int nbase = blockIdx.y * 128;
    const int tid = threadIdx.x;
    const int w = tid >> 6, lane = tid & 63;
    const int lm = lane & 15, q4 = lane >> 4;
    const int wr = (w >> 1) * 64, wc = (w & 1) * 64;
    const int lrow = lane >> 3, lsw = ((lane & 7) ^ lrow) * 8;

    const bf16* A  = Xcat + (size_t)slab * 4096 * 1024;
    const bf16* Bt = Wqkv + (size_t)slab * 1024 * 1024;

    f32x4 acc[4][4] = {};

    auto stage = [&](int k0, int d) {
        #pragma unroll
        for (int i = 0; i < 4; i++) {
            int c = w * 4 + i;
            gl2lds16(&A [(size_t)(mbase + c * 8 + lrow) * 1024 + k0 + lsw], &Al[d][c * 512]);
            gl2lds16(&Bt[(size_t)(nbase + c * 8 + lrow) * 1024 + k0 + lsw], &Bl[d][c * 512]);
        }
    };

    stage(0, 0);

    for (int t = 0; t < 16; t++) {
        __syncthreads();                      // buf[t&1] ready (loads had a full
        if (t < 15) stage((t + 1) * 64, (t + 1) & 1);   // compute phase to land)
        const bf16* Ad = &Al[t & 1][0];
        const bf16* Bd = &Bl[t & 1][0];
        __builtin_amdgcn_s_setprio(1);
        #pragma unroll
        for (int kk2 = 0; kk2 < 2; kk2++) {
            bf16x8 a[4], bfr[4];
            const int g = ((kk2 * 4 + q4) ^ (lm & 7)) * 8;
            #pragma unroll
            for (int i = 0; i < 4; i++) a[i]   = *(const bf16x8*)&Ad[(wr + i * 16 + lm) * 64 + g];
            #pragma unroll
            for (int j = 0; j < 4; j++) bfr[j] = *(const bf16x8*)&Bd[(wc + j * 16 + lm) * 64 + g];
            #pragma unroll
            for (int i = 0; i < 4; i++)
                #pragma unroll
                for (int j = 0; j < 4; j++)
                    acc[i][j] = MFMA16(a[i], bfr[j], acc[i][j]);
        }
        __builtin_amdgcn_s_setprio(0);
    }

    if (slab == 2) {
        #pragma unroll
        for (int i = 0; i < 4; i++)
            #pragma unroll
            for (int j = 0; j < 4; j++) {
                int s0  = mbase + wr + i * 16 + q4 * 4;      // kv, multiple of 4
                int col = nbase + wc + j * 16 + lm;          // e
                int sp  = (s0 & ~31) | (((s0 >> 2) & 3) * 8) | (((s0 >> 4) & 1) * 4);
                bf16x4 p = { (bf16)acc[i][j][0], (bf16)acc[i][j][1],
                             (bf16)acc[i][j][2], (bf16)acc[i][j][3] };
                *(bf16x4*)&Vt[(size_t)col * 4096 + sp] = p;
            }
    } else {
        bf16* C = (slab == 0) ? Cq : Ck;
        const float scale = (slab == 0) ? qscale : 1.0f;
        #pragma unroll
        for (int i = 0; i < 4; i++)
            #pragma unroll
            for (int j = 0; j < 4; j++)
                #pragma unroll
                for (int r = 0; r < 4; r++) {
                    int row = mbase + wr + i * 16 + q4 * 4 + r;
                    int col = nbase + wc + j * 16 + lm;
                    C[(size_t)row * 1024 + col] = (bf16)(acc[i][j][r] * scale);
                }
    }
}

// ---------------------------------------------------------------------------
// Output projection, 64x128 (MxN) tiles, grid (64, 8).
// out[4096,1024] fp32 = Hd bf16 @ Wot^T. Double-buffered schedule.
// ---------------------------------------------------------------------------
__global__ __launch_bounds__(256)
void outproj_gemm(const bf16* __restrict__ A, const bf16* __restrict__ Bt,
                  float* __restrict__ C)
{
    __shared__ bf16 Al[2][64 * 64];
    __shared__ bf16 Bl[2][128 * 64];
    const int mbase = blockIdx.x * 64;
    const int nbase = blockIdx.y * 128;
    const int tid = threadIdx.x;
    const int w = tid >> 6, lane = tid & 63;
    const int lm = lane & 15, q4 = lane >> 4;
    const int wm = (w >> 1) * 32, wn = (w & 1) * 64;   // 32x64 per wave
    const int lrow = lane >> 3, lsw = ((lane & 7) ^ lrow) * 8;

    f32x4 acc[2][4] = {};

    auto stage = [&](int k0, int d) {
        #pragma unroll
        for (int i = 0; i < 2; i++) {
            int c = w * 2 + i;                          // 8 chunks of 8 rows
            gl2lds16(&A[(size_t)(mbase + c * 8 + lrow) * 1024 + k0 + lsw], &Al[d][c * 512]);
        }
        #pragma unroll
        for (int i = 0; i < 4; i++) {
            int c = w * 4 + i;                          // 16 chunks of 8 rows
            gl2lds16(&Bt[(size_t)(nbase + c * 8 + lrow) * 1024 + k0 + lsw], &Bl[d][c * 512]);
        }
    };

    stage(0, 0);

    for (int t = 0; t < 16; t++) {
        __syncthreads();
        if (t < 15) stage((t + 1) * 64, (t + 1) & 1);
        const bf16* Ad = &Al[t & 1][0];
        const bf16* Bd = &Bl[t & 1][0];
        __builtin_amdgcn_s_setprio(1);
        #pragma unroll
        for (int kk2 = 0; kk2 < 2; kk2++) {
            bf16x8 a[2], bfr[4];
            const int g = ((kk2 * 4 + q4) ^ (lm & 7)) * 8;
            #pragma unroll
            for (int i = 0; i < 2; i++) a[i]   = *(const bf16x8*)&Ad[(wm + i * 16 + lm) * 64 + g];
            #pragma unroll
            for (int j = 0; j < 4; j++) bfr[j] = *(const bf16x8*)&Bd[(wn + j * 16 + lm) * 64 + g];
            #pragma unroll
            for (int i = 0; i < 2; i++)
                #pragma unroll
                for (int j = 0; j < 4; j++)
                    acc[i][j] = MFMA16(a[i], bfr[j], acc[i][j]);
        }
        __builtin_amdgcn_s_setprio(0);
    }

    #pragma unroll
    for (int i = 0; i < 2; i++)
        #pragma unroll
        for (int j = 0; j < 4; j++)
            #pragma unroll
            for (int r = 0; r < 4; r++) {
                int row = mbase + wm + i * 16 + q4 * 4 + r;
                int col = nbase + wn + j * 16 + lm;
                C[(size_t)row * 1024 + col] = acc[i][j][r];
            }
}

// ---------------------------------------------------------------------------
// Flash attention. Round-5: per-wave footprint 32q -> 64q (4 q-strips).
// LDS traffic is set by per-wave qxkv footprint (round-4 analysis): each K/V
// fragment now feeds 4 MFMAs instead of 2 -> per-CU LDS reads halve
// (128->64 KB/tile) and staging writes halve (2 blocks/CU stage vs 4).
//   Block = 128 q rows: 4 waves = 2 q-groups (p) x 2 kv-halves (kvh).
//   Grid (16,2,16) = 512 blocks = 2 blocks/CU = 2 waves/SIMD; ILP from the
//   4 independent strips covers the lower TLP.
//   Kept: XCD swizzle (512 = 8*64; each XCD owns 4 complete (b,h) groups),
//   kv-permuted Vt, XOR LDS swizzle, Lacc denom-via-MFMA, setprio,
//   double-buffer stage-before-compute, f32 LDS merge of kv-halves.
// ---------------------------------------------------------------------------
__global__ __launch_bounds__(256, 2)
void attn_kernel(const bf16* __restrict__ Qp, const bf16* __restrict__ Kp,
                 const bf16* __restrict__ Vt, bf16* __restrict__ Hd)
{
    __shared__ bf16 KV[4][64 * 64];     // [0,1]=K dbuf, [2,3]=V dbuf; 32 KB
    __shared__ float Ls[128];           // denom merge scratch

    // XCD-aware remap (8 XCDs, 512 blocks, bijective: 512 = 8*64)
    const int n  = blockIdx.x + 16 * (blockIdx.y + 2 * blockIdx.z);
    const int m  = (n & 7) * 64 + (n >> 3);
    const int qt = m & 15, bh = m >> 4;
    const int b  = bh & 1,  h  = bh >> 1;

    const int qbase = qt * 128;
    const int tid  = threadIdx.x;
    const int w    = tid >> 6, lane = tid & 63;
    const int p    = w & 1;          // q-group: rows [p*64, p*64+64)
    const int kvh  = w >> 1;         // kv half of each 64-wide tile
    const int lm   = lane & 15, q4 = lane >> 4;
    const int lrow = lane >> 3, lsw = ((lane & 7) ^ lrow) * 8;

    const bf16* Qh = Qp + (size_t)(b * 2048 + qbase + p * 64) * 1024 + h * 64;
    const bf16* Kh = Kp + (size_t)(b * 2048) * 1024 + h * 64;
    const bf16* Vh = Vt + (size_t)(h * 64) * 4096 + b * 2048;

    // Q fragments (loop-invariant), B-operand layout: n=lm, k=q4*8+j
    bf16x8 Qf[4][2];
    #pragma unroll
    for (int i = 0; i < 4; i++)
        #pragma unroll
        for (int kk2 = 0; kk2 < 2; kk2++)
            Qf[i][kk2] = *(const bf16x8*)&Qh[(size_t)(i * 16 + lm) * 1024 + kk2 * 32 + q4 * 8];

    const bf16 one = (bf16)1.0f;
    const bf16x8 ones = { one, one, one, one, one, one, one, one };

    f32x4 O[4][4] = {};
    f32x4 Lacc[4] = {};   // row-sums of P (softmax denom), same row layout as O

    // stage kv-tile kt into buffer d (K rows=kv, V rows=e; identical pattern)
    auto stage = [&](int kt, int d) {
        #pragma unroll
        for (int i = 0; i < 2; i++) {
            int c = w * 2 + i;                           // 8 chunks of 8 rows
            gl2lds16(&Kh[(size_t)(kt * 64 + c * 8 + lrow) * 1024 + lsw], &KV[d][c * 512]);
            gl2lds16(&Vh[(size_t)(c * 8 + lrow) * 4096 + kt * 64 + lsw], &KV[2 + d][c * 512]);
        }
    };

    stage(0, 0);

    for (int it = 0; it < 32; it++) {
        __syncthreads();                                 // buf[it&1] ready
        if (it < 31) stage(it + 1, (it + 1) & 1);        // overlap with compute
        const bf16* Kd = &KV[it & 1][0];
        const bf16* Vd = &KV[2 + (it & 1)][0];

        // S^T for this wave's kv-half: ctp in {kvh*2, kvh*2+1}; 4 q-strips
        f32x4 St[4][2] = {};
        __builtin_amdgcn_s_setprio(1);
        #pragma unroll
        for (int c2 = 0; c2 < 2; c2++) {
            const int ctp = kvh * 2 + c2;
            #pragma unroll
            for (int kk2 = 0; kk2 < 2; kk2++) {
                const int g = ((kk2 * 4 + q4) ^ (lm & 7)) * 8;
                bf16x8 kf = *(const bf16x8*)&Kd[(ctp * 16 + lm) * 64 + g];
                #pragma unroll
                for (int i = 0; i < 4; i++)
                    St[i][c2] = MFMA16(kf, Qf[i][kk2], St[i][c2]);
            }
        }
        __builtin_amdgcn_s_setprio(0);

        // P = exp2(S^T) packed into A-slots for this kv-32 chunk
        bf16x8 Pf[4];
        #pragma unroll
        for (int i = 0; i < 4; i++)
            #pragma unroll
            for (int j = 0; j < 8; j++)
                Pf[i][j] = (bf16)__builtin_amdgcn_exp2f(St[i][j >> 2][j & 3]);

        __builtin_amdgcn_s_setprio(1);
        #pragma unroll
        for (int i = 0; i < 4; i++) Lacc[i] = MFMA16(Pf[i], ones, Lacc[i]);
        const int gv = ((kvh * 4 + q4) ^ (lm & 7)) * 8;
        #pragma unroll
        for (int et = 0; et < 4; et++) {
            bf16x8 vf = *(const bf16x8*)&Vd[(et * 16 + lm) * 64 + gv];
            #pragma unroll
            for (int i = 0; i < 4; i++)
                O[i][et] = MFMA16(Pf[i], vf, O[i][et]);
        }
        __builtin_amdgcn_s_setprio(0);
    }

    // ---- merge the two kv-halves via LDS (Ol aliases all of KV: 32 KB) ----
    __syncthreads();                       // last tile's reads done
    float* Ol = (float*)&KV[0][0];         // [p][64 rows][64 cols] f32
    if (kvh == 1) {
        #pragma unroll
        for (int i = 0; i < 4; i++)
            #pragma unroll
            for (int et = 0; et < 4; et++)
                #pragma unroll
                for (int r = 0; r < 4; r++)
                    Ol[(p * 64 + i * 16 + q4 * 4 + r) * 64 + et * 16 + lm] = O[i][et][r];
        if (lm == 0) {
            #pragma unroll
            for (int i = 0; i < 4; i++)
                #pragma unroll
                for (int r = 0; r < 4; r++)
                    Ls[p * 64 + i * 16 + q4 * 4 + r] = Lacc[i][r];
        }
    }
    __syncthreads();
    if (kvh == 0) {
        #pragma unroll
        for (int i = 0; i < 4; i++) {
            float rl[4];
            #pragma unroll
            for (int r = 0; r < 4; r++)
                rl[r] = 1.0f / (Lacc[i][r] + Ls[p * 64 + i * 16 + q4 * 4 + r]);
            #pragma unroll
            for (int et = 0; et < 4; et++)
                #pragma unroll
                for (int r = 0; r < 4; r++) {
                    float o = O[i][et][r] +
                              Ol[(p * 64 + i * 16 + q4 * 4 + r) * 64 + et * 16 + lm];
                    int row = b * 2048 + qbase + p * 64 + i * 16 + q4 * 4 + r;
                    Hd[(size_t)row * 1024 + h * 64 + et * 16 + lm] = (bf16)(o * rl[r]);
                }
        }
    }
}

extern "C" void kernel_launch(void* const* d_in, const int* in_sizes, int n_in,
                              void* d_out, int out_size, void* d_ws, size_t ws_size,
                              hipStream_t stream)
{
    const float* q  = (const float*)d_in[0];
    const float* k  = (const float*)d_in[1];
    const float* v  = (const float*)d_in[2];
    const float* Wq = (const float*)d_in[3];
    const float* Wk = (const float*)d_in[4];
    const float* Wv = (const float*)d_in[5];
    const float* Wo = (const float*)d_in[6];
    float* out = (float*)d_out;

    // ws (bf16 elems, Mi = 1024*1024; 24Mi = 48 MB):
    //  [ 0, 4) qb -> Hd (attn out; qb dead after qkv_gemm)   [ 4, 8) kb
    //  [ 8,12) vb    [12,15) Wqkv   [15,16) Wot   [16,20) Qproj   [20,24) Kproj
    // Vt (bf16, 8 MB, kv-permuted) lives in d_out (16 MB fp32), overwritten
    // by outproj at the very end.
    const size_t Mi = 1024 * 1024;
    bf16* Xcat  = (bf16*)d_ws;
    bf16* Hd    = Xcat;                   // alias qb
    bf16* Wqkv  = Xcat + 12 * Mi;
    bf16* Wot   = Xcat + 15 * Mi;
    bf16* Qproj = Xcat + 16 * Mi;
    bf16* Kproj = Xcat + 20 * Mi;
    bf16* Vtb   = (bf16*)d_out;

    const float qscale = 0.125f * 1.4426950408889634f;  // 1/sqrt(64) * log2(e)

    prep_kernel<<<7168, 256, 0, stream>>>(q, k, v, Wq, Wk, Wv, Wo, Xcat, Wqkv, Wot);
    qkv_gemm<<<dim3(96, 8), 256, 0, stream>>>(Xcat, Wqkv, Qproj, Kproj, Vtb, qscale);
    attn_kernel<<<dim3(16, 2, 16), 256, 0, stream>>>(Qproj, Kproj, Vtb, Hd);
    outproj_gemm<<<dim3(64, 8), 256, 0, stream>>>(Hd, Wot, out);
}

// Round 6
// 198.633 us; speedup vs baseline: 1.2360x; 1.0180x over previous
//
#include <hip/hip_runtime.h>
#include <hip/hip_bf16.h>

typedef __bf16 bf16;
typedef __bf16 bf16x8 __attribute__((ext_vector_type(8)));
typedef __bf16 bf16x4 __attribute__((ext_vector_type(4)));
typedef float  f32x4  __attribute__((ext_vector_type(4)));

#define MFMA16(a,b,c) __builtin_amdgcn_mfma_f32_16x16x32_bf16(a, b, c, 0, 0, 0)

// async global->LDS, 16B per lane; lds dst is wave-uniform base + lane*16
__device__ __forceinline__ void gl2lds16(const bf16* g, bf16* l) {
    __builtin_amdgcn_global_load_lds(
        (__attribute__((address_space(1))) void*)g,
        (__attribute__((address_space(3))) void*)l, 16, 0, 0);
}

// ---------------------------------------------------------------------------
// Fused prep: blocks [0,6144) fp32->bf16 cvt of q|k|v; [6144,6912) Wq/Wk/Wv
// transpose; [6912,7168) Wo transpose.
// ---------------------------------------------------------------------------
__global__ __launch_bounds__(256)
void prep_kernel(const float* __restrict__ q, const float* __restrict__ k,
                 const float* __restrict__ v, const float* __restrict__ Wq,
                 const float* __restrict__ Wk, const float* __restrict__ Wv,
                 const float* __restrict__ Wo, bf16* __restrict__ Xcat,
                 bf16* __restrict__ Wqkv, bf16* __restrict__ Wot)
{
    __shared__ bf16 Tl[64][72];
    const int bid = blockIdx.x;
    const int tid = threadIdx.x;

    if (bid < 6144) {
        int gidx = bid * 256 + tid;                   // vec8 group
        int t    = gidx >> 19;
        int off  = (gidx & 0x7FFFF) * 8;
        const float* src = (t == 0) ? q : (t == 1) ? k : v;
        const float4 f0 = *(const float4*)&src[off];
        const float4 f1 = *(const float4*)&src[off + 4];
        bf16x8 p = { (bf16)f0.x, (bf16)f0.y, (bf16)f0.z, (bf16)f0.w,
                     (bf16)f1.x, (bf16)f1.y, (bf16)f1.z, (bf16)f1.w };
        *(bf16x8*)&Xcat[(size_t)gidx * 8] = p;
        return;
    }
    if (bid < 6912) {
        // W[h][k][e] fp32 -> Wqkv[t*1Mi + (h*64+e)*1024 + k]
        int idx = bid - 6144;                         // 768
        int x = idx & 15, z = idx >> 4;               // x: k-tile, z = t*16+h
        int t = z >> 4, h = z & 15;
        const float* inp = ((t == 0) ? Wq : (t == 1) ? Wk : Wv) + (size_t)h * 65536;
        bf16* outp = Wqkv + (size_t)t * 1024 * 1024 + (size_t)h * 65536;
        int r0 = x * 64;
        #pragma unroll
        for (int i = 0; i < 2; i++) {
            int s = tid + i * 256;
            int r = s >> 3, c8 = (s & 7) * 8;
            const float* ap = &inp[(size_t)(r0 + r) * 64 + c8];
            float4 f0 = *(const float4*)ap;
            float4 f1 = *(const float4*)(ap + 4);
            bf16x8 p = { (bf16)f0.x, (bf16)f0.y, (bf16)f0.z, (bf16)f0.w,
                         (bf16)f1.x, (bf16)f1.y, (bf16)f1.z, (bf16)f1.w };
            *(bf16x8*)&Tl[r][c8] = p;
        }
        __syncthreads();
        #pragma unroll
        for (int i = 0; i < 2; i++) {
            int s = tid + i * 256;
            int c = s >> 3, r8 = (s & 7) * 8;
            bf16x8 p;
            #pragma unroll
            for (int j = 0; j < 8; j++) p[j] = Tl[r8 + j][c];
            *(bf16x8*)&outp[(size_t)c * 1024 + r0 + r8] = p;
        }
        return;
    }
    // Wo[h][e][o] fp32 -> Wot[o][h*64+e]
    {
        int idx = bid - 6912;                         // 256
        int y = idx & 15, h = idx >> 4;
        int c0 = y * 64;
        const float* inp = Wo + (size_t)h * 65536;
        bf16* outp = Wot + (size_t)h * 64;
        #pragma unroll
        for (int i = 0; i < 2; i++) {
            int s = tid + i * 256;
            int r = s >> 3, c8 = (s & 7) * 8;
            const float* ap = &inp[(size_t)r * 1024 + c0 + c8];
            float4 f0 = *(const float4*)ap;
            float4 f1 = *(const float4*)(ap + 4);
            bf16x8 p = { (bf16)f0.x, (bf16)f0.y, (bf16)f0.z, (bf16)f0.w,
                         (bf16)f1.x, (bf16)f1.y, (bf16)f1.z, (bf16)f1.w };
            *(bf16x8*)&Tl[r][c8] = p;
        }
        __syncthreads();
        #pragma unroll
        for (int i = 0; i < 2; i++) {
            int s = tid + i * 256;
            int c = s >> 3, r8 = (s & 7) * 8;
            bf16x8 p;
            #pragma unroll
            for (int j = 0; j < 8; j++) p[j] = Tl[r8 + j][c];
            *(bf16x8*)&outp[(size_t)(c0 + c) * 1024 + r8] = p;
        }
    }
}

// ---------------------------------------------------------------------------
// Fused QKV projection GEMM: grid (96, 8); slab = blockIdx.x>>5 in {0,1,2}.
// slab 0 -> Qproj (scaled), slab 1 -> Kproj, slab 2 -> Vt transposed epilogue
// with the 32-block kv PERMUTATION: pos(s) = (s&~31) | ((s>>2)&3)*8 |
// ((s>>4)&1)*4 | (s&3), so attn V-fragments are contiguous b128 reads.
// Double-buffered LDS + stage(t+1)-before-compute(t) + one barrier per K-tile.
// ---------------------------------------------------------------------------
__global__ __launch_bounds__(256)
void qkv_gemm(const bf16* __restrict__ Xcat, const bf16* __restrict__ Wqkv,
              bf16* __restrict__ Cq, bf16* __restrict__ Ck, bf16* __restrict__ Vt,
              float qscale)
{
    __shared__ bf16 Al[2][128 * 64];
    __shared__ bf16 Bl[2][128 * 64];
    const int slab  = blockIdx.x >> 5;
    const int mbase = (blockIdx.x & 31) * 128;
    const int nbase = blockIdx.y * 128;
    const int tid = threadIdx.x;
    const int w = tid >> 6, lane = tid & 63;
    const int lm = lane & 15, q4 = lane >> 4;
    const int wr = (w >> 1) * 64, wc = (w & 1) * 64;
    const int lrow = lane >> 3, lsw = ((lane & 7) ^ lrow) * 8;

    const bf16* A  = Xcat + (size_t)slab * 4096 * 1024;
    const bf16* Bt = Wqkv + (size_t)slab * 1024 * 1024;

    f32x4 acc[4][4] = {};

    auto stage = [&](int k0, int d) {
        #pragma unroll
        for (int i = 0; i < 4; i++) {
            int c = w * 4 + i;
            gl2lds16(&A [(size_t)(mbase + c * 8 + lrow) * 1024 + k0 + lsw], &Al[d][c * 512]);
            gl2lds16(&Bt[(size_t)(nbase + c * 8 + lrow) * 1024 + k0 + lsw], &Bl[d][c * 512]);
        }
    };

    stage(0, 0);

    for (int t = 0; t < 16; t++) {
        __syncthreads();                      // buf[t&1] ready (loads had a full
        if (t < 15) stage((t + 1) * 64, (t + 1) & 1);   // compute phase to land)
        const bf16* Ad = &Al[t & 1][0];
        const bf16* Bd = &Bl[t & 1][0];
        __builtin_amdgcn_s_setprio(1);
        #pragma unroll
        for (int kk2 = 0; kk2 < 2; kk2++) {
            bf16x8 a[4], bfr[4];
            const int g = ((kk2 * 4 + q4) ^ (lm & 7)) * 8;
            #pragma unroll
            for (int i = 0; i < 4; i++) a[i]   = *(const bf16x8*)&Ad[(wr + i * 16 + lm) * 64 + g];
            #pragma unroll
            for (int j = 0; j < 4; j++) bfr[j] = *(const bf16x8*)&Bd[(wc + j * 16 + lm) * 64 + g];
            #pragma unroll
            for (int i = 0; i < 4; i++)
                #pragma unroll
                for (int j = 0; j < 4; j++)
                    acc[i][j] = MFMA16(a[i], bfr[j], acc[i][j]);
        }
        __builtin_amdgcn_s_setprio(0);
    }

    if (slab == 2) {
        #pragma unroll
        for (int i = 0; i < 4; i++)
            #pragma unroll
            for (int j = 0; j < 4; j++) {
                int s0  = mbase + wr + i * 16 + q4 * 4;      // kv, multiple of 4
                int col = nbase + wc + j * 16 + lm;          // e
                int sp  = (s0 & ~31) | (((s0 >> 2) & 3) * 8) | (((s0 >> 4) & 1) * 4);
                bf16x4 p = { (bf16)acc[i][j][0], (bf16)acc[i][j][1],
                             (bf16)acc[i][j][2], (bf16)acc[i][j][3] };
                *(bf16x4*)&Vt[(size_t)col * 4096 + sp] = p;
            }
    } else {
        bf16* C = (slab == 0) ? Cq : Ck;
        const float scale = (slab == 0) ? qscale : 1.0f;
        #pragma unroll
        for (int i = 0; i < 4; i++)
            #pragma unroll
            for (int j = 0; j < 4; j++)
                #pragma unroll
                for (int r = 0; r < 4; r++) {
                    int row = mbase + wr + i * 16 + q4 * 4 + r;
                    int col = nbase + wc + j * 16 + lm;
                    C[(size_t)row * 1024 + col] = (bf16)(acc[i][j][r] * scale);
                }
    }
}

// ---------------------------------------------------------------------------
// Output projection, 64x128 (MxN) tiles, grid (64, 8).
// out[4096,1024] fp32 = Hd bf16 @ Wot^T. Double-buffered schedule.
// ---------------------------------------------------------------------------
__global__ __launch_bounds__(256)
void outproj_gemm(const bf16* __restrict__ A, const bf16* __restrict__ Bt,
                  float* __restrict__ C)
{
    __shared__ bf16 Al[2][64 * 64];
    __shared__ bf16 Bl[2][128 * 64];
    const int mbase = blockIdx.x * 64;
    const int nbase = blockIdx.y * 128;
    const int tid = threadIdx.x;
    const int w = tid >> 6, lane = tid & 63;
    const int lm = lane & 15, q4 = lane >> 4;
    const int wm = (w >> 1) * 32, wn = (w & 1) * 64;   // 32x64 per wave
    const int lrow = lane >> 3, lsw = ((lane & 7) ^ lrow) * 8;

    f32x4 acc[2][4] = {};

    auto stage = [&](int k0, int d) {
        #pragma unroll
        for (int i = 0; i < 2; i++) {
            int c = w * 2 + i;                          // 8 chunks of 8 rows
            gl2lds16(&A[(size_t)(mbase + c * 8 + lrow) * 1024 + k0 + lsw], &Al[d][c * 512]);
        }
        #pragma unroll
        for (int i = 0; i < 4; i++) {
            int c = w * 4 + i;                          // 16 chunks of 8 rows
            gl2lds16(&Bt[(size_t)(nbase + c * 8 + lrow) * 1024 + k0 + lsw], &Bl[d][c * 512]);
        }
    };

    stage(0, 0);

    for (int t = 0; t < 16; t++) {
        __syncthreads();
        if (t < 15) stage((t + 1) * 64, (t + 1) & 1);
        const bf16* Ad = &Al[t & 1][0];
        const bf16* Bd = &Bl[t & 1][0];
        __builtin_amdgcn_s_setprio(1);
        #pragma unroll
        for (int kk2 = 0; kk2 < 2; kk2++) {
            bf16x8 a[2], bfr[4];
            const int g = ((kk2 * 4 + q4) ^ (lm & 7)) * 8;
            #pragma unroll
            for (int i = 0; i < 2; i++) a[i]   = *(const bf16x8*)&Ad[(wm + i * 16 + lm) * 64 + g];
            #pragma unroll
            for (int j = 0; j < 4; j++) bfr[j] = *(const bf16x8*)&Bd[(wn + j * 16 + lm) * 64 + g];
            #pragma unroll
            for (int i = 0; i < 2; i++)
                #pragma unroll
                for (int j = 0; j < 4; j++)
                    acc[i][j] = MFMA16(a[i], bfr[j], acc[i][j]);
        }
        __builtin_amdgcn_s_setprio(0);
    }

    #pragma unroll
    for (int i = 0; i < 2; i++)
        #pragma unroll
        for (int j = 0; j < 4; j++)
            #pragma unroll
            for (int r = 0; r < 4; r++) {
                int row = mbase + wm + i * 16 + q4 * 4 + r;
                int col = nbase + wn + j * 16 + lm;
                C[(size_t)row * 1024 + col] = acc[i][j][r];
            }
}

// ---------------------------------------------------------------------------
// Flash attention. Round-6: cross-tile software pipeline.
// Round-5 counters: MfmaUtil 33 + VALUBusy 34, sum 67% -> serial phase
// alternation (S-MFMA -> exp-VALU -> PV-MFMA) leaves each pipe idle during
// the other's phase, with only 2 lockstep waves/SIMD to cover.
// Fix: carry St across tiles in ping-pong registers (StA/StB, 2x-unrolled
// loop for static indexing); per iteration the region after the barrier is
//   stage(t+2) ; S(t+1) [MFMA, writes StNext] ; exp(t)+PV(t) [VALU+MFMA,
//   reads StCur]
// -> S(t+1) MFMAs and exp(t) VALU are independent, one scheduling region,
// compiler interleaves them. 3 LDS buffers (48 KB) so stage(t+2) never
// collides with PV(t)'s reads -> still one barrier per tile.
//   Kept: XCD swizzle, 64q-per-wave footprint, kv-permuted Vt, XOR LDS
//   swizzle, Lacc denom-via-MFMA, setprio, f32 LDS merge of kv-halves.
// ---------------------------------------------------------------------------
__global__ __launch_bounds__(256, 2)
void attn_kernel(const bf16* __restrict__ Qp, const bf16* __restrict__ Kp,
                 const bf16* __restrict__ Vt, bf16* __restrict__ Hd)
{
    __shared__ bf16 KV[6][64 * 64];     // [0..2]=K trio, [3..5]=V trio; 48 KB
    __shared__ float Ls[128];           // denom merge scratch

    // XCD-aware remap (8 XCDs, 512 blocks, bijective: 512 = 8*64)
    const int n  = blockIdx.x + 16 * (blockIdx.y + 2 * blockIdx.z);
    const int m  = (n & 7) * 64 + (n >> 3);
    const int qt = m & 15, bh = m >> 4;
    const int b  = bh & 1,  h  = bh >> 1;

    const int qbase = qt * 128;
    const int tid  = threadIdx.x;
    const int w    = tid >> 6, lane = tid & 63;
    const int p    = w & 1;          // q-group: rows [p*64, p*64+64)
    const int kvh  = w >> 1;         // kv half of each 64-wide tile
    const int lm   = lane & 15, q4 = lane >> 4;
    const int lrow = lane >> 3, lsw = ((lane & 7) ^ lrow) * 8;

    const bf16* Qh = Qp + (size_t)(b * 2048 + qbase + p * 64) * 1024 + h * 64;
    const bf16* Kh = Kp + (size_t)(b * 2048) * 1024 + h * 64;
    const bf16* Vh = Vt + (size_t)(h * 64) * 4096 + b * 2048;

    // Q fragments (loop-invariant), B-operand layout: n=lm, k=q4*8+j
    bf16x8 Qf[4][2];
    #pragma unroll
    for (int i = 0; i < 4; i++)
        #pragma unroll
        for (int kk2 = 0; kk2 < 2; kk2++)
            Qf[i][kk2] = *(const bf16x8*)&Qh[(size_t)(i * 16 + lm) * 1024 + kk2 * 32 + q4 * 8];

    const bf16 one = (bf16)1.0f;
    const bf16x8 ones = { one, one, one, one, one, one, one, one };

    f32x4 O[4][4] = {};
    f32x4 Lacc[4] = {};     // row-sums of P (softmax denom), same layout as O
    f32x4 StA[4][2], StB[4][2];   // ping-pong S^T carried across tiles

    // stage kv-tile kt into (kd, vd) (K rows=kv, V rows=e; identical pattern)
    auto stage = [&](int kt, bf16* kd, bf16* vd) {
        #pragma unroll
        for (int i = 0; i < 2; i++) {
            int c = w * 2 + i;                           // 8 chunks of 8 rows
            gl2lds16(&Kh[(size_t)(kt * 64 + c * 8 + lrow) * 1024 + lsw], &kd[c * 512]);
            gl2lds16(&Vh[(size_t)(c * 8 + lrow) * 4096 + kt * 64 + lsw], &vd[c * 512]);
        }
    };

    // S^T of one tile into St (zeroed here); wave's kv-half: ctp = kvh*2+c2
    auto S_step = [&](const bf16* Kd, f32x4 (&St)[4][2]) {
        #pragma unroll
        for (int i = 0; i < 4; i++)
            #pragma unroll
            for (int c2 = 0; c2 < 2; c2++)
                St[i][c2] = f32x4{0.f, 0.f, 0.f, 0.f};
        #pragma unroll
        for (int c2 = 0; c2 < 2; c2++) {
            const int ctp = kvh * 2 + c2;
            #pragma unroll
            for (int kk2 = 0; kk2 < 2; kk2++) {
                const int g = ((kk2 * 4 + q4) ^ (lm & 7)) * 8;
                bf16x8 kf = *(const bf16x8*)&Kd[(ctp * 16 + lm) * 64 + g];
                #pragma unroll
                for (int i = 0; i < 4; i++)
                    St[i][c2] = MFMA16(kf, Qf[i][kk2], St[i][c2]);
            }
        }
    };

    // exp(St) -> Pf; Lacc += Pf*1; O += Pf*V   (reads St, never writes it)
    auto PV_step = [&](const bf16* Vd, const f32x4 (&St)[4][2]) {
        bf16x8 Pf[4];
        #pragma unroll
        for (int i = 0; i < 4; i++)
            #pragma unroll
            for (int j = 0; j < 8; j++)
                Pf[i][j] = (bf16)__builtin_amdgcn_exp2f(St[i][j >> 2][j & 3]);
        #pragma unroll
        for (int i = 0; i < 4; i++) Lacc[i] = MFMA16(Pf[i], ones, Lacc[i]);
        const int gv = ((kvh * 4 + q4) ^ (lm & 7)) * 8;
        #pragma unroll
        for (int et = 0; et < 4; et++) {
            bf16x8 vf = *(const bf16x8*)&Vd[(et * 16 + lm) * 64 + gv];
            #pragma unroll
            for (int i = 0; i < 4; i++)
                O[i][et] = MFMA16(Pf[i], vf, O[i][et]);
        }
    };

    // rotating buffer trio: cX0 = tile t, cX1 = tile t+1, cX2 = free (t+2)
    bf16 *cK0 = &KV[0][0], *cK1 = &KV[1][0], *cK2 = &KV[2][0];
    bf16 *cV0 = &KV[3][0], *cV1 = &KV[4][0], *cV2 = &KV[5][0];

    stage(0, cK0, cV0);
    stage(1, cK1, cV1);
    __syncthreads();                     // tiles 0,1 resident
    S_step(cK0, StA);                    // St(0)

    #pragma unroll 1
    for (int t2 = 0; t2 < 15; t2++) {
        // ---- tile it = 2*t2 (cur StA, next StB) ----
        __syncthreads();                 // stage(it+1) landed; PV(it-1) done
        stage(2 * t2 + 2, cK2, cV2);     // free buffer
        __builtin_amdgcn_s_setprio(1);
        S_step(cK1, StB);                // S(it+1): MFMA, indep of StA
        PV_step(cV0, StA);               // exp(it)+PV(it): VALU+MFMA
        __builtin_amdgcn_s_setprio(0);
        { bf16* t = cK0; cK0 = cK1; cK1 = cK2; cK2 = t;
          t = cV0; cV0 = cV1; cV1 = cV2; cV2 = t; }
        // ---- tile it = 2*t2+1 (cur StB, next StA) ----
        __syncthreads();
        stage(2 * t2 + 3, cK2, cV2);
        __builtin_amdgcn_s_setprio(1);
        S_step(cK1, StA);
        PV_step(cV0, StB);
        __builtin_amdgcn_s_setprio(0);
        { bf16* t = cK0; cK0 = cK1; cK1 = cK2; cK2 = t;
          t = cV0; cV0 = cV1; cV1 = cV2; cV2 = t; }
    }
    // tile 30: no stage left; S(31); PV(30)
    __syncthreads();
    __builtin_amdgcn_s_setprio(1);
    S_step(cK1, StB);
    PV_step(cV0, StA);
    __builtin_amdgcn_s_setprio(0);
    { bf16* t = cK0; cK0 = cK1; cK1 = cK2; cK2 = t;
      t = cV0; cV0 = cV1; cV1 = cV2; cV2 = t; }
    // tile 31: PV only (K/V long resident)
    PV_step(cV0, StB);

    // ---- merge the two kv-halves via LDS (Ol aliases KV: 32 of 48 KB) ----
    __syncthreads();                       // all PV reads done
    float* Ol = (float*)&KV[0][0];         // [p][64 rows][64 cols] f32
    if (kvh == 1) {
        #pragma unroll
        for (int i = 0; i < 4; i++)
            #pragma unroll
            for (int et = 0; et < 4; et++)
                #pragma unroll
                for (int r = 0; r < 4; r++)
                    Ol[(p * 64 + i * 16 + q4 * 4 + r) * 64 + et * 16 + lm] = O[i][et][r];
        if (lm == 0) {
            #pragma unroll
            for (int i = 0; i < 4; i++)
                #pragma unroll
                for (int r = 0; r < 4; r++)
                    Ls[p * 64 + i * 16 + q4 * 4 + r] = Lacc[i][r];
        }
    }
    __syncthreads();
    if (kvh == 0) {
        #pragma unroll
        for (int i = 0; i < 4; i++) {
            float rl[4];
            #pragma unroll
            for (int r = 0; r < 4; r++)
                rl[r] = 1.0f / (Lacc[i][r] + Ls[p * 64 + i * 16 + q4 * 4 + r]);
            #pragma unroll
            for (int et = 0; et < 4; et++)
                #pragma unroll
                for (int r = 0; r < 4; r++) {
                    float o = O[i][et][r] +
                              Ol[(p * 64 + i * 16 + q4 * 4 + r) * 64 + et * 16 + lm];
                    int row = b * 2048 + qbase + p * 64 + i * 16 + q4 * 4 + r;
                    Hd[(size_t)row * 1024 + h * 64 + et * 16 + lm] = (bf16)(o * rl[r]);
                }
        }
    }
}

extern "C" void kernel_launch(void* const* d_in, const int* in_sizes, int n_in,
                              void* d_out, int out_size, void* d_ws, size_t ws_size,
                              hipStream_t stream)
{
    const float* q  = (const float*)d_in[0];
    const float* k  = (const float*)d_in[1];
    const float* v  = (const float*)d_in[2];
    const float* Wq = (const float*)d_in[3];
    const float* Wk = (const float*)d_in[4];
    const float* Wv = (const float*)d_in[5];
    const float* Wo = (const float*)d_in[6];
    float* out = (float*)d_out;

    // ws (bf16 elems, Mi = 1024*1024; 24Mi = 48 MB):
    //  [ 0, 4) qb -> Hd (attn out; qb dead after qkv_gemm)   [ 4, 8) kb
    //  [ 8,12) vb    [12,15) Wqkv   [15,16) Wot   [16,20) Qproj   [20,24) Kproj
    // Vt (bf16, 8 MB, kv-permuted) lives in d_out (16 MB fp32), overwritten
    // by outproj at the very end.
    const size_t Mi = 1024 * 1024;
    bf16* Xcat  = (bf16*)d_ws;
    bf16* Hd    = Xcat;                   // alias qb
    bf16* Wqkv  = Xcat + 12 * Mi;
    bf16* Wot   = Xcat + 15 * Mi;
    bf16* Qproj = Xcat + 16 * Mi;
    bf16* Kproj = Xcat + 20 * Mi;
    bf16* Vtb   = (bf16*)d_out;

    const float qscale = 0.125f * 1.4426950408889634f;  // 1/sqrt(64) * log2(e)

    prep_kernel<<<7168, 256, 0, stream>>>(q, k, v, Wq, Wk, Wv, Wo, Xcat, Wqkv, Wot);
    qkv_gemm<<<dim3(96, 8), 256, 0, stream>>>(Xcat, Wqkv, Qproj, Kproj, Vtb, qscale);
    attn_kernel<<<dim3(16, 2, 16), 256, 0, stream>>>(Qproj, Kproj, Vtb, Hd);
    outproj_gemm<<<dim3(64, 8), 256, 0, stream>>>(Hd, Wot, out);
}